// Round 4
// baseline (509.434 us; speedup 1.0000x reference)
//
#include <hip/hip_runtime.h>
#include <stdint.h>

#define V 50257
#define B_ 64
#define S_ 8
#define ROWS (B_ * S_)
#define L_ 2048
#define NEG_INF -1000000000.0f
#define MASK_WORDS_PER_B 1571   // ceil(50257/32)
#define MASK_WORDS_TOTAL (B_ * MASK_WORDS_PER_B)   // 100544 words = 402176 B
#define TOTAL (ROWS * V)        // 25,731,584
#define NVEC (TOTAL / 4)        // 6,432,896 (exact)
#define TOP_CAP 64              // top-k=50 plus headroom for exact ties at kth
#define CAP 1024                // per-row candidate slots (expect ~412 +- 20)
#define TRAW 2.4f               // raw-value gather cutoff (== 3.0 * 0.8 exactly)
#define GBLOCKS 2048

// ---- workspace layout (new fast path) ----
#define WS_ROWTHRESH 0          // 512 f32
#define WS_ROWTIE    2048       // 512 i32
#define WS_GCNT      4096       // 512 u32 (+pad)
#define WS_MASK      8192       // 402176 B -> ends at 410368
#define WS_GCAND     413696     // 512 * 1024 * 8 B = 4194304
#define WS_NEED      (WS_GCAND + (size_t)ROWS * CAP * 8)
// zero range covers gcnt (incl. pad) + mask: [4096, 410368)
#define ZERO_WORDS   ((WS_MASK - WS_GCNT + MASK_WORDS_TOTAL * 4) / 4)

__device__ __forceinline__ unsigned fkey(float f) {
    unsigned u = __float_as_uint(f);
    return (u & 0x80000000u) ? ~u : (u | 0x80000000u);
}

__global__ __launch_bounds__(256) void zero_kernel(unsigned* __restrict__ p, int n) {
    int i = blockIdx.x * 256 + threadIdx.x;
    if (i < n) p[i] = 0u;
}

__global__ __launch_bounds__(256) void build_mask_kernel(const int* __restrict__ ids,
                                                         unsigned* __restrict__ mask) {
    int i = blockIdx.x * 256 + threadIdx.x;
    if (i >= B_ * L_) return;
    int t = ids[i];
    int b = i >> 11;  // L_ = 2048
    atomicOr(&mask[b * MASK_WORDS_PER_B + (t >> 5)], 1u << (t & 31));
}

// ---------------- fast path: gather + select ----------------

__device__ __forceinline__ void emit_cand(uint2* __restrict__ gcand,
                                          unsigned* __restrict__ gcnt,
                                          unsigned ee, float val) {
    unsigned r = ee / (unsigned)V;          // magic-mul
    unsigned tok = ee - r * (unsigned)V;
    unsigned p = atomicAdd(&gcnt[r], 1u);
    if (p < CAP) gcand[((size_t)r << 10) + p] = make_uint2(__float_as_uint(val), tok);
}

// Streaming gather of raw values v >= TRAW into per-row candidate buffers.
// Candidate SET per row is deterministic (pure predicate); slot order is not,
// but select_kernel sorts by (value, index) so the final output is exact.
__global__ __launch_bounds__(256) void gather_kernel(const float4* __restrict__ in4,
                                                     uint2* __restrict__ gcand,
                                                     unsigned* __restrict__ gcnt) {
    const int stride = 256 * GBLOCKS;
    for (int i = blockIdx.x * 256 + threadIdx.x; i < NVEC; i += stride) {
        float4 a = in4[i];
        bool p0 = a.x >= TRAW, p1 = a.y >= TRAW, p2 = a.z >= TRAW, p3 = a.w >= TRAW;
        if (p0 | p1 | p2 | p3) {
            unsigned e = (unsigned)i << 2;
            if (p0) emit_cand(gcand, gcnt, e, a.x);
            if (p1) emit_cand(gcand, gcnt, e + 1u, a.y);
            if (p2) emit_cand(gcand, gcnt, e + 2u, a.z);
            if (p3) emit_cand(gcand, gcnt, e + 3u, a.w);
        }
    }
}

// One wave per row. Exact reference semantics incl. fp32 ties: kth = 50th
// largest of x=v/0.8; kept = ALL x >= kth; stable (value desc, index asc)
// order like np.argsort(-x); f64 softmax+cumsum decision.
__global__ __launch_bounds__(64) void select_kernel(const float* __restrict__ logits,
                                                    const uint2* __restrict__ gcand,
                                                    const unsigned* __restrict__ gcnt,
                                                    float* __restrict__ rowThresh,
                                                    int* __restrict__ rowTie) {
    const int row = blockIdx.x;
    const int lane = threadIdx.x;
    __shared__ float cV[CAP];
    __shared__ int   cI[CAP];
    __shared__ float sVal[TOP_CAP];
    __shared__ int   sIdx[TOP_CAP];
    __shared__ double sExp[TOP_CAP];
    __shared__ int s_c;

    int cnt = (int)gcnt[row];
    const float* rp = logits + (size_t)row * V;

    if (cnt >= 50 && cnt <= CAP) {
        for (int j = lane; j < cnt; j += 64) {
            uint2 u = gcand[((size_t)row << 10) + j];
            cV[j] = __uint_as_float(u.x) / 0.8f;
            cI[j] = (int)u.y;
        }
    } else {
        // Pathological-only fallback (never taken on this data): exact bisect in
        // raw key space for the 50th-largest, then re-gather with 2-ulp slack
        // (guards the rare case where /0.8 merges distinct raw values into ties).
        unsigned lo = 0u, hi = 0xFFFFFFFFu;
        while (lo < hi) {
            unsigned mid = lo + ((hi - lo) >> 1) + 1u;
            int c = 0;
            for (int j = lane; j < V; j += 64) c += (int)(fkey(rp[j]) >= mid);
#pragma unroll
            for (int off = 32; off; off >>= 1) c += __shfl_xor(c, off);
            if (c >= 50) lo = mid; else hi = mid - 1u;
        }
        unsigned gl = (lo > 2u) ? lo - 2u : 0u;
        if (lane == 0) s_c = 0;
        __syncthreads();
        for (int j = lane; j < V; j += 64) {
            float v = rp[j];
            if (fkey(v) >= gl) {
                int p = atomicAdd(&s_c, 1);
                if (p < CAP) { cV[p] = v / 0.8f; cI[p] = j; }
            }
        }
        __syncthreads();
        cnt = s_c < CAP ? s_c : CAP;
    }
    __syncthreads();

    // Per-lane register slots (CAP/64 = 16). All indexing compile-time constant.
    float lv[16];
    int li[16];
#pragma unroll
    for (int k = 0; k < 16; ++k) {
        int j = lane + (k << 6);
        bool ok = j < cnt;
        lv[k] = ok ? cV[j] : -3.4e38f;
        li[k] = ok ? cI[j] : 0x7FFFFFFF;
    }

    // Extract-max 50 + ties: local argmax over 16 regs, 6-step shfl_xor wave
    // argmax (key: value desc, token idx asc), remove winner by unique idx.
    float kth = 0.0f;
    int M = 0;
    for (int r = 0; r < TOP_CAP; ++r) {
        float bv = lv[0];
        int bi = li[0];
#pragma unroll
        for (int k = 1; k < 16; ++k)
            if (lv[k] > bv || (lv[k] == bv && li[k] < bi)) { bv = lv[k]; bi = li[k]; }
        float wv = bv;
        int wi = bi;
#pragma unroll
        for (int off = 1; off < 64; off <<= 1) {
            float ov = __shfl_xor(wv, off);
            int oi = __shfl_xor(wi, off);
            if (ov > wv || (ov == wv && oi < wi)) { wv = ov; wi = oi; }
        }
        if (r >= 50 && wv != kth) break;   // uniform (wv uniform after reduce)
        if (lane == 0) { sVal[r] = wv; sIdx[r] = wi; }
        M = r + 1;
        if (r == 49) kth = wv;
#pragma unroll
        for (int k = 0; k < 16; ++k)
            if (li[k] == wi) { lv[k] = -3.4e38f; li[k] = 0x7FFFFFFF; }
    }
    __syncthreads();

    // f64 softmax + cumsum decision (same numerics as the validated round-3 path:
    // serial denom and cum on lane 0).
    if (lane < M) sExp[lane] = exp((double)sVal[lane] - (double)sVal[0]);
    __syncthreads();
    if (lane == 0) {
        double denom = 0.0;
        for (int i = 0; i < M; ++i) denom += sExp[i];
        double cum = 0.0;
        int J = M - 1;
        for (int i = 0; i < M; ++i) {
            cum += sExp[i] / denom;
            if (cum > 0.9) { J = i; break; }
        }
        rowThresh[row] = sVal[J];
        rowTie[row] = sIdx[J];   // among x == thresh, keep token index <= this
    }
}

// ---------------- safety fallback path (round-3 kernel, ws too small) ----------------
#define CAND_CAP 4096
#define FIN_CAP 1024
#define RT_THREADS 1024

__device__ __forceinline__ int blockReduceSum(int v, int tid, int* s16) {
#pragma unroll
    for (int off = 32; off; off >>= 1) v += __shfl_down(v, off);
    __syncthreads();
    if ((tid & 63) == 0) s16[tid >> 6] = v;
    __syncthreads();
    int t = 0;
#pragma unroll
    for (int k = 0; k < RT_THREADS / 64; ++k) t += s16[k];
    return t;
}

__global__ __launch_bounds__(RT_THREADS, 8) void row_thresh_kernel(
        const float* __restrict__ logits, float* __restrict__ rowThresh,
        int* __restrict__ rowTie) {
    const int tid = threadIdx.x;
    const int row = blockIdx.x;
    if (row >= ROWS) return;
    const float* rp = logits + (size_t)row * V;

    __shared__ float candV[CAND_CAP];
    __shared__ int   candI[CAND_CAP];
    __shared__ float finV[FIN_CAP];
    __shared__ int   finI[FIN_CAP];
    __shared__ float sVal[TOP_CAP];
    __shared__ int   sIdx[TOP_CAP];
    __shared__ double sExp[TOP_CAP];
    __shared__ int s_cnt, s_M;
    __shared__ int s_red[RT_THREADS / 64];

    const unsigned mis = (unsigned)(((size_t)row * (size_t)V) & 3u);
    const int a0 = (int)((4u - mis) & 3u);
    const int nv = (V - a0) >> 2;
    const int tailStart = a0 + (nv << 2);
    const float4* vp = reinterpret_cast<const float4*>(rp + a0);

    float TR = 2.4f;
    int cnt = 0;
    for (int attempt = 0; attempt < 12; ++attempt) {
        if (tid == 0) s_cnt = 0;
        __syncthreads();
        for (int base = tid; base < nv; base += 4 * RT_THREADS) {
            int i1 = base + RT_THREADS, i2 = base + 2 * RT_THREADS, i3 = base + 3 * RT_THREADS;
            float4 a = vp[base];
            float4 b = vp[i1 < nv ? i1 : nv - 1];
            float4 c = vp[i2 < nv ? i2 : nv - 1];
            float4 d = vp[i3 < nv ? i3 : nv - 1];
            float va[16] = {a.x, a.y, a.z, a.w, b.x, b.y, b.z, b.w,
                            c.x, c.y, c.z, c.w, d.x, d.y, d.z, d.w};
            int ib[4] = {base, i1, i2, i3};
            bool ok[4] = {true, i1 < nv, i2 < nv, i3 < nv};
#pragma unroll
            for (int q = 0; q < 4; ++q) {
                if (!ok[q]) continue;
#pragma unroll
                for (int cc = 0; cc < 4; ++cc) {
                    float v = va[q * 4 + cc];
                    if (v >= TR) {
                        int p = atomicAdd(&s_cnt, 1);
                        if (p < CAND_CAP) { candV[p] = v / 0.8f; candI[p] = a0 + (ib[q] << 2) + cc; }
                    }
                }
            }
        }
        if (tid < a0) {
            float v = rp[tid];
            if (v >= TR) {
                int p = atomicAdd(&s_cnt, 1);
                if (p < CAND_CAP) { candV[p] = v / 0.8f; candI[p] = tid; }
            }
        }
        if (tid < V - tailStart) {
            float v = rp[tailStart + tid];
            if (v >= TR) {
                int p = atomicAdd(&s_cnt, 1);
                if (p < CAND_CAP) { candV[p] = v / 0.8f; candI[p] = tailStart + tid; }
            }
        }
        __syncthreads();
        cnt = s_cnt;
        if (cnt >= 50 && cnt <= CAND_CAP) break;
        if (cnt < 50) TR -= 1.2f; else TR += 1.2f;
        __syncthreads();
    }
    if (cnt > CAND_CAP) cnt = CAND_CAP;

    const float* fV;
    const int* fI;
    int F;
    if (cnt <= FIN_CAP) {
        fV = candV; fI = candI; F = cnt;
    } else {
        unsigned lo = fkey(TR / 0.8f) - 1u;
        unsigned hi = 0xFFFFFFFFu;
        while (lo < hi) {
            unsigned mid = lo + ((hi - lo) >> 1) + 1u;
            int c = 0;
            for (int i = tid; i < cnt; i += RT_THREADS) c += (int)(fkey(candV[i]) >= mid);
            c = blockReduceSum(c, tid, s_red);
            if (c >= 50) lo = mid; else hi = mid - 1u;
        }
        __syncthreads();
        if (tid == 0) s_cnt = 0;
        __syncthreads();
        for (int i = tid; i < cnt; i += RT_THREADS) {
            if (fkey(candV[i]) >= lo) {
                int p = atomicAdd(&s_cnt, 1);
                if (p < FIN_CAP) { finV[p] = candV[i]; finI[p] = candI[i]; }
            }
        }
        __syncthreads();
        F = s_cnt < FIN_CAP ? s_cnt : FIN_CAP;
        fV = finV; fI = finI;
    }

    if (tid < TOP_CAP) { sVal[tid] = -3.4e38f; sIdx[tid] = 0x7FFFFFFF; }
    __syncthreads();

    {
        float v0 = (tid < F) ? fV[tid] : -3.4e38f;
        int i0 = (tid < F) ? fI[tid] : 0x7FFFFFFF;
        int r0 = 0;
        for (int j = 0; j < F; ++j) {
            float w = fV[j];
            int wi = fI[j];
            r0 += (w > v0) || (w == v0 && wi < i0);
        }
        if (tid < F && r0 < TOP_CAP) { sVal[r0] = v0; sIdx[r0] = i0; }
    }
    __syncthreads();

    if (tid == 0) {
        float kth = sVal[49];
        int M = 50;
        while (M < TOP_CAP && sVal[M] == kth) ++M;
        s_M = M;
    }
    __syncthreads();
    int M = s_M;
    if (tid < M) sExp[tid] = exp((double)sVal[tid] - (double)sVal[0]);
    __syncthreads();

    if (tid == 0) {
        double denom = 0.0;
#pragma unroll 1
        for (int i = 0; i < M; ++i) denom += sExp[i];
        double cum = 0.0;
        int J = M - 1;
#pragma unroll 1
        for (int i = 0; i < M; ++i) {
            cum += sExp[i] / denom;
            if (cum > 0.9) { J = i; break; }
        }
        rowThresh[row] = sVal[J];
        rowTie[row] = sIdx[J];
    }
}

// ---------------- apply ----------------

__global__ __launch_bounds__(256) void apply_kernel(const float4* __restrict__ in4,
                                                    const float* __restrict__ rowThresh,
                                                    const int* __restrict__ rowTie,
                                                    const unsigned* __restrict__ mask,
                                                    float4* __restrict__ out4) {
    int idx = blockIdx.x * 256 + threadIdx.x;
    if (idx >= NVEC) return;
    unsigned e = (unsigned)idx << 2;
    unsigned row = e / (unsigned)V;
    unsigned rem = e - row * (unsigned)V;
    float4 v = in4[idx];
    float xs[4] = {v.x, v.y, v.z, v.w};
    float o[4];
    float t0 = rowThresh[row];
    int ti0 = rowTie[row];
    bool crosses = (rem + 3u >= (unsigned)V);
    float t1 = crosses ? rowThresh[row + 1] : t0;
    int ti1 = crosses ? rowTie[row + 1] : ti0;
#pragma unroll
    for (int c = 0; c < 4; ++c) {
        unsigned tok = rem + (unsigned)c;
        unsigned r = row;
        float t = t0;
        int ti = ti0;
        if (tok >= (unsigned)V) { tok -= (unsigned)V; r = row + 1u; t = t1; ti = ti1; }
        float x = xs[c] / 0.8f;
        bool keep = (x > t) || (x == t && (int)tok <= ti);
        float oo = keep ? x : NEG_INF;
        if ((r & 7u) == 7u) {
            unsigned w = mask[(r >> 3) * MASK_WORDS_PER_B + (tok >> 5)];
            if ((w >> (tok & 31u)) & 1u) oo = (oo < 0.0f) ? oo * 1.2f : oo / 1.2f;
        }
        o[c] = oo;
    }
    out4[idx] = make_float4(o[0], o[1], o[2], o[3]);
}

extern "C" void kernel_launch(void* const* d_in, const int* in_sizes, int n_in,
                              void* d_out, int out_size, void* d_ws, size_t ws_size,
                              hipStream_t stream) {
    const float* logits = (const float*)d_in[0];
    const int* ids = (const int*)d_in[1];
    float* out = (float*)d_out;

    float* rowThresh = (float*)((char*)d_ws + WS_ROWTHRESH);
    int* rowTie = (int*)((char*)d_ws + WS_ROWTIE);
    unsigned* gcnt = (unsigned*)((char*)d_ws + WS_GCNT);
    unsigned* mask = (unsigned*)((char*)d_ws + WS_MASK);
    uint2* gcand = (uint2*)((char*)d_ws + WS_GCAND);

    if (ws_size >= WS_NEED) {
        // fast path: zero(gcnt+mask) -> build mask -> gather -> select -> apply
        zero_kernel<<<(ZERO_WORDS + 255) / 256, 256, 0, stream>>>(gcnt, ZERO_WORDS);
        build_mask_kernel<<<(B_ * L_) / 256, 256, 0, stream>>>(ids, mask);
        gather_kernel<<<GBLOCKS, 256, 0, stream>>>((const float4*)logits, gcand, gcnt);
        select_kernel<<<ROWS, 64, 0, stream>>>(logits, gcand, gcnt, rowThresh, rowTie);
    } else {
        zero_kernel<<<(MASK_WORDS_TOTAL + 255) / 256, 256, 0, stream>>>(mask, MASK_WORDS_TOTAL);
        build_mask_kernel<<<(B_ * L_) / 256, 256, 0, stream>>>(ids, mask);
        row_thresh_kernel<<<ROWS, RT_THREADS, 0, stream>>>(logits, rowThresh, rowTie);
    }
    apply_kernel<<<(NVEC + 255) / 256, 256, 0, stream>>>((const float4*)logits, rowThresh, rowTie,
                                                         mask, (float4*)out);
}

// Round 5
// 132.376 us; speedup vs baseline: 3.8484x; 3.8484x over previous
//
#include <hip/hip_runtime.h>
#include <stdint.h>

#define V 50257
#define B_ 64
#define S_ 8
#define ROWS (B_ * S_)
#define L_ 2048
#define NEG_INF -1000000000.0f
#define MASK_WORDS_PER_B 1571   // ceil(50257/32)
#define MASK_WORDS_TOTAL (B_ * MASK_WORDS_PER_B)   // 100544 words = 402176 B
#define TOTAL (ROWS * V)        // 25,731,584
#define NVEC (TOTAL / 4)        // 6,432,896 (exact)
#define TOP_CAP 64              // top-k=50 plus headroom for exact ties at kth
#define CAP 1024                // per-row candidate slots (expect ~412 +- 20)
#define TRAW 2.4f               // raw-value gather cutoff (== 3.0 * 0.8 exactly)
#define GBLK_F4 1571            // float4s per gather block (spans <= 2 rows)
#define GBLOCKS_G ((NVEC + GBLK_F4 - 1) / GBLK_F4)   // 4095
#define GCAP 512                // per-block LDS candidate cap (mean ~52, sd ~7)
#define GCNT_STRIDE 32          // u32s; one counter per 128-B line (no false sharing)

// ---- workspace layout ----
#define WS_ROWTHRESH 0                          // 512 f32
#define WS_ROWTIE    2048                       // 512 i32
#define WS_GCNT      4096                       // 512 counters @ 128-B stride = 65536 B
#define WS_MASK      (WS_GCNT + ROWS * GCNT_STRIDE * 4)      // 69632
#define WS_GCAND     (WS_MASK + MASK_WORDS_TOTAL * 4)        // 471808 (8-aligned)
#define WS_NEED      (WS_GCAND + (size_t)ROWS * CAP * 8)     // ~4.45 MB
// zero range covers gcnt region + mask contiguously
#define ZERO_WORDS   ((ROWS * GCNT_STRIDE * 4 + MASK_WORDS_TOTAL * 4) / 4)

__device__ __forceinline__ unsigned fkey(float f) {
    unsigned u = __float_as_uint(f);
    return (u & 0x80000000u) ? ~u : (u | 0x80000000u);
}

__global__ __launch_bounds__(256) void zero_kernel(unsigned* __restrict__ p, int n) {
    int i = blockIdx.x * 256 + threadIdx.x;
    if (i < n) p[i] = 0u;
}

__global__ __launch_bounds__(256) void build_mask_kernel(const int* __restrict__ ids,
                                                         unsigned* __restrict__ mask) {
    int i = blockIdx.x * 256 + threadIdx.x;
    if (i >= B_ * L_) return;
    int t = ids[i];
    int b = i >> 11;  // L_ = 2048
    atomicOr(&mask[b * MASK_WORDS_PER_B + (t >> 5)], 1u << (t & 31));
}

// ---------------- fast path: gather (block-aggregated) + select ----------------

// Each block owns float4 range [blk*GBLK_F4, min(+GBLK_F4, NVEC)) — spans at
// most 2 rows. Candidates (raw v >= TRAW) buffer in LDS; at the end, <= 2
// global atomicAdds reserve per-row ranges, then burst-write. Candidate SET per
// row is deterministic; slot order is not, but select sorts by (value, index).
__global__ __launch_bounds__(256) void gather_kernel(const float4* __restrict__ in4,
                                                     uint2* __restrict__ gcand,
                                                     unsigned* __restrict__ gcnt) {
    const int blk = blockIdx.x;
    const int tid = threadIdx.x;
    const int start = blk * GBLK_F4;
    const int end = min(start + GBLK_F4, NVEC);

    __shared__ uint2 buf[GCAP];          // (element index ee, raw value bits)
    __shared__ int lcnt, c0, base0, base1, w0, w1;
    if (tid == 0) { lcnt = 0; c0 = 0; w0 = 0; w1 = 0; }
    __syncthreads();

    for (int i = start + tid; i < end; i += 256) {
        float4 a = in4[i];
        bool p0 = a.x >= TRAW, p1 = a.y >= TRAW, p2 = a.z >= TRAW, p3 = a.w >= TRAW;
        if (p0 | p1 | p2 | p3) {
            unsigned e = (unsigned)i << 2;
            if (p0) { int p = atomicAdd(&lcnt, 1); if (p < GCAP) buf[p] = make_uint2(e,      __float_as_uint(a.x)); }
            if (p1) { int p = atomicAdd(&lcnt, 1); if (p < GCAP) buf[p] = make_uint2(e + 1u, __float_as_uint(a.y)); }
            if (p2) { int p = atomicAdd(&lcnt, 1); if (p < GCAP) buf[p] = make_uint2(e + 2u, __float_as_uint(a.z)); }
            if (p3) { int p = atomicAdd(&lcnt, 1); if (p < GCAP) buf[p] = make_uint2(e + 3u, __float_as_uint(a.w)); }
        }
    }
    __syncthreads();

    const int cnt = lcnt;
    const int take = cnt < GCAP ? cnt : GCAP;
    const unsigned rlo = (unsigned)(((size_t)start * 4) / V);
    const unsigned rhi = (unsigned)(((size_t)end * 4 - 1) / V);

    for (int j = tid; j < take; j += 256)
        if (buf[j].x / (unsigned)V == rlo) atomicAdd(&c0, 1);
    __syncthreads();

    if (tid == 0) {
        base0 = (int)atomicAdd(&gcnt[rlo * GCNT_STRIDE], (unsigned)c0);
        int c1 = take - c0;
        base1 = (c1 > 0) ? (int)atomicAdd(&gcnt[rhi * GCNT_STRIDE], (unsigned)c1) : 0;
        if (cnt > GCAP) {   // LDS overflow (never on this data): force exact fallback
            atomicAdd(&gcnt[rlo * GCNT_STRIDE], 1000000u);
            atomicAdd(&gcnt[rhi * GCNT_STRIDE], 1000000u);
        }
    }
    __syncthreads();

    for (int j = tid; j < take; j += 256) {
        unsigned ee = buf[j].x, vb = buf[j].y;
        unsigned r = ee / (unsigned)V;
        unsigned tok = ee - r * (unsigned)V;
        int p = (r == rlo) ? base0 + atomicAdd(&w0, 1) : base1 + atomicAdd(&w1, 1);
        if (p < CAP) gcand[((size_t)r << 10) + p] = make_uint2(vb, tok);
    }
}

// One wave per row. Exact reference semantics incl. fp32 ties: kth = 50th
// largest of x=v/0.8; kept = ALL x >= kth; stable (value desc, index asc)
// order like np.argsort(-x); f64 softmax+cumsum decision.
__global__ __launch_bounds__(64) void select_kernel(const float* __restrict__ logits,
                                                    const uint2* __restrict__ gcand,
                                                    const unsigned* __restrict__ gcnt,
                                                    float* __restrict__ rowThresh,
                                                    int* __restrict__ rowTie) {
    const int row = blockIdx.x;
    const int lane = threadIdx.x;
    __shared__ float cV[CAP];
    __shared__ int   cI[CAP];
    __shared__ float sVal[TOP_CAP];
    __shared__ int   sIdx[TOP_CAP];
    __shared__ double sExp[TOP_CAP];
    __shared__ int s_c;

    int cnt = (int)gcnt[row * GCNT_STRIDE];
    const float* rp = logits + (size_t)row * V;

    if (cnt >= 50 && cnt <= CAP) {
        for (int j = lane; j < cnt; j += 64) {
            uint2 u = gcand[((size_t)row << 10) + j];
            cV[j] = __uint_as_float(u.x) / 0.8f;
            cI[j] = (int)u.y;
        }
    } else {
        // Pathological-only fallback: exact bisect in raw key space for the
        // 50th-largest, then re-gather with 2-ulp slack (covers /0.8 merging
        // distinct raw values into equal x).
        unsigned lo = 0u, hi = 0xFFFFFFFFu;
        while (lo < hi) {
            unsigned mid = lo + ((hi - lo) >> 1) + 1u;
            int c = 0;
            for (int j = lane; j < V; j += 64) c += (int)(fkey(rp[j]) >= mid);
#pragma unroll
            for (int off = 32; off; off >>= 1) c += __shfl_xor(c, off);
            if (c >= 50) lo = mid; else hi = mid - 1u;
        }
        unsigned gl = (lo > 2u) ? lo - 2u : 0u;
        if (lane == 0) s_c = 0;
        __syncthreads();
        for (int j = lane; j < V; j += 64) {
            float v = rp[j];
            if (fkey(v) >= gl) {
                int p = atomicAdd(&s_c, 1);
                if (p < CAP) { cV[p] = v / 0.8f; cI[p] = j; }
            }
        }
        __syncthreads();
        cnt = s_c < CAP ? s_c : CAP;
    }
    __syncthreads();

    // Per-lane register slots (CAP/64 = 16); all indexing compile-time constant.
    float lv[16];
    int li[16];
#pragma unroll
    for (int k = 0; k < 16; ++k) {
        int j = lane + (k << 6);
        bool ok = j < cnt;
        lv[k] = ok ? cV[j] : -3.4e38f;
        li[k] = ok ? cI[j] : 0x7FFFFFFF;
    }

    // Extract-max 50 + kth ties: local argmax over 16 regs, 6-step shfl_xor wave
    // argmax (key: value desc, token idx asc), remove winner by unique idx.
    float kth = 0.0f;
    int M = 0;
    for (int r = 0; r < TOP_CAP; ++r) {
        float bv = lv[0];
        int bi = li[0];
#pragma unroll
        for (int k = 1; k < 16; ++k)
            if (lv[k] > bv || (lv[k] == bv && li[k] < bi)) { bv = lv[k]; bi = li[k]; }
        float wv = bv;
        int wi = bi;
#pragma unroll
        for (int off = 1; off < 64; off <<= 1) {
            float ov = __shfl_xor(wv, off);
            int oi = __shfl_xor(wi, off);
            if (ov > wv || (ov == wv && oi < wi)) { wv = ov; wi = oi; }
        }
        if (r >= 50 && wv != kth) break;   // uniform after reduce
        if (lane == 0) { sVal[r] = wv; sIdx[r] = wi; }
        M = r + 1;
        if (r == 49) kth = wv;
#pragma unroll
        for (int k = 0; k < 16; ++k)
            if (li[k] == wi) { lv[k] = -3.4e38f; li[k] = 0x7FFFFFFF; }
    }
    __syncthreads();

    if (lane < M) sExp[lane] = exp((double)sVal[lane] - (double)sVal[0]);
    __syncthreads();
    if (lane == 0) {
        double denom = 0.0;
        for (int i = 0; i < M; ++i) denom += sExp[i];
        double cum = 0.0;
        int J = M - 1;
        for (int i = 0; i < M; ++i) {
            cum += sExp[i] / denom;
            if (cum > 0.9) { J = i; break; }
        }
        rowThresh[row] = sVal[J];
        rowTie[row] = sIdx[J];   // among x == thresh, keep token index <= this
    }
}

// ---------------- safety fallback path (round-3 kernel, ws too small) ----------------
#define CAND_CAP 4096
#define FIN_CAP 1024
#define RT_THREADS 1024

__device__ __forceinline__ int blockReduceSum(int v, int tid, int* s16) {
#pragma unroll
    for (int off = 32; off; off >>= 1) v += __shfl_down(v, off);
    __syncthreads();
    if ((tid & 63) == 0) s16[tid >> 6] = v;
    __syncthreads();
    int t = 0;
#pragma unroll
    for (int k = 0; k < RT_THREADS / 64; ++k) t += s16[k];
    return t;
}

__global__ __launch_bounds__(RT_THREADS, 8) void row_thresh_kernel(
        const float* __restrict__ logits, float* __restrict__ rowThresh,
        int* __restrict__ rowTie) {
    const int tid = threadIdx.x;
    const int row = blockIdx.x;
    if (row >= ROWS) return;
    const float* rp = logits + (size_t)row * V;

    __shared__ float candV[CAND_CAP];
    __shared__ int   candI[CAND_CAP];
    __shared__ float finV[FIN_CAP];
    __shared__ int   finI[FIN_CAP];
    __shared__ float sVal[TOP_CAP];
    __shared__ int   sIdx[TOP_CAP];
    __shared__ double sExp[TOP_CAP];
    __shared__ int s_cnt, s_M;
    __shared__ int s_red[RT_THREADS / 64];

    const unsigned mis = (unsigned)(((size_t)row * (size_t)V) & 3u);
    const int a0 = (int)((4u - mis) & 3u);
    const int nv = (V - a0) >> 2;
    const int tailStart = a0 + (nv << 2);
    const float4* vp = reinterpret_cast<const float4*>(rp + a0);

    float TR = 2.4f;
    int cnt = 0;
    for (int attempt = 0; attempt < 12; ++attempt) {
        if (tid == 0) s_cnt = 0;
        __syncthreads();
        for (int base = tid; base < nv; base += 4 * RT_THREADS) {
            int i1 = base + RT_THREADS, i2 = base + 2 * RT_THREADS, i3 = base + 3 * RT_THREADS;
            float4 a = vp[base];
            float4 b = vp[i1 < nv ? i1 : nv - 1];
            float4 c = vp[i2 < nv ? i2 : nv - 1];
            float4 d = vp[i3 < nv ? i3 : nv - 1];
            float va[16] = {a.x, a.y, a.z, a.w, b.x, b.y, b.z, b.w,
                            c.x, c.y, c.z, c.w, d.x, d.y, d.z, d.w};
            int ib[4] = {base, i1, i2, i3};
            bool ok[4] = {true, i1 < nv, i2 < nv, i3 < nv};
#pragma unroll
            for (int q = 0; q < 4; ++q) {
                if (!ok[q]) continue;
#pragma unroll
                for (int cc = 0; cc < 4; ++cc) {
                    float v = va[q * 4 + cc];
                    if (v >= TR) {
                        int p = atomicAdd(&s_cnt, 1);
                        if (p < CAND_CAP) { candV[p] = v / 0.8f; candI[p] = a0 + (ib[q] << 2) + cc; }
                    }
                }
            }
        }
        if (tid < a0) {
            float v = rp[tid];
            if (v >= TR) {
                int p = atomicAdd(&s_cnt, 1);
                if (p < CAND_CAP) { candV[p] = v / 0.8f; candI[p] = tid; }
            }
        }
        if (tid < V - tailStart) {
            float v = rp[tailStart + tid];
            if (v >= TR) {
                int p = atomicAdd(&s_cnt, 1);
                if (p < CAND_CAP) { candV[p] = v / 0.8f; candI[p] = tailStart + tid; }
            }
        }
        __syncthreads();
        cnt = s_cnt;
        if (cnt >= 50 && cnt <= CAND_CAP) break;
        if (cnt < 50) TR -= 1.2f; else TR += 1.2f;
        __syncthreads();
    }
    if (cnt > CAND_CAP) cnt = CAND_CAP;

    const float* fV;
    const int* fI;
    int F;
    if (cnt <= FIN_CAP) {
        fV = candV; fI = candI; F = cnt;
    } else {
        unsigned lo = fkey(TR / 0.8f) - 1u;
        unsigned hi = 0xFFFFFFFFu;
        while (lo < hi) {
            unsigned mid = lo + ((hi - lo) >> 1) + 1u;
            int c = 0;
            for (int i = tid; i < cnt; i += RT_THREADS) c += (int)(fkey(candV[i]) >= mid);
            c = blockReduceSum(c, tid, s_red);
            if (c >= 50) lo = mid; else hi = mid - 1u;
        }
        __syncthreads();
        if (tid == 0) s_cnt = 0;
        __syncthreads();
        for (int i = tid; i < cnt; i += RT_THREADS) {
            if (fkey(candV[i]) >= lo) {
                int p = atomicAdd(&s_cnt, 1);
                if (p < FIN_CAP) { finV[p] = candV[i]; finI[p] = candI[i]; }
            }
        }
        __syncthreads();
        F = s_cnt < FIN_CAP ? s_cnt : FIN_CAP;
        fV = finV; fI = finI;
    }

    if (tid < TOP_CAP) { sVal[tid] = -3.4e38f; sIdx[tid] = 0x7FFFFFFF; }
    __syncthreads();

    {
        float v0 = (tid < F) ? fV[tid] : -3.4e38f;
        int i0 = (tid < F) ? fI[tid] : 0x7FFFFFFF;
        int r0 = 0;
        for (int j = 0; j < F; ++j) {
            float w = fV[j];
            int wi = fI[j];
            r0 += (w > v0) || (w == v0 && wi < i0);
        }
        if (tid < F && r0 < TOP_CAP) { sVal[r0] = v0; sIdx[r0] = i0; }
    }
    __syncthreads();

    if (tid == 0) {
        float kth = sVal[49];
        int M = 50;
        while (M < TOP_CAP && sVal[M] == kth) ++M;
        s_M = M;
    }
    __syncthreads();
    int M = s_M;
    if (tid < M) sExp[tid] = exp((double)sVal[tid] - (double)sVal[0]);
    __syncthreads();

    if (tid == 0) {
        double denom = 0.0;
#pragma unroll 1
        for (int i = 0; i < M; ++i) denom += sExp[i];
        double cum = 0.0;
        int J = M - 1;
#pragma unroll 1
        for (int i = 0; i < M; ++i) {
            cum += sExp[i] / denom;
            if (cum > 0.9) { J = i; break; }
        }
        rowThresh[row] = sVal[J];
        rowTie[row] = sIdx[J];
    }
}

// ---------------- apply ----------------

__global__ __launch_bounds__(256) void apply_kernel(const float4* __restrict__ in4,
                                                    const float* __restrict__ rowThresh,
                                                    const int* __restrict__ rowTie,
                                                    const unsigned* __restrict__ mask,
                                                    float4* __restrict__ out4) {
    int idx = blockIdx.x * 256 + threadIdx.x;
    if (idx >= NVEC) return;
    unsigned e = (unsigned)idx << 2;
    unsigned row = e / (unsigned)V;
    unsigned rem = e - row * (unsigned)V;
    float4 v = in4[idx];
    float xs[4] = {v.x, v.y, v.z, v.w};
    float o[4];
    float t0 = rowThresh[row];
    int ti0 = rowTie[row];
    bool crosses = (rem + 3u >= (unsigned)V);
    float t1 = crosses ? rowThresh[row + 1] : t0;
    int ti1 = crosses ? rowTie[row + 1] : ti0;
#pragma unroll
    for (int c = 0; c < 4; ++c) {
        unsigned tok = rem + (unsigned)c;
        unsigned r = row;
        float t = t0;
        int ti = ti0;
        if (tok >= (unsigned)V) { tok -= (unsigned)V; r = row + 1u; t = t1; ti = ti1; }
        float x = xs[c] / 0.8f;
        bool keep = (x > t) || (x == t && (int)tok <= ti);
        float oo = keep ? x : NEG_INF;
        if ((r & 7u) == 7u) {
            unsigned w = mask[(r >> 3) * MASK_WORDS_PER_B + (tok >> 5)];
            if ((w >> (tok & 31u)) & 1u) oo = (oo < 0.0f) ? oo * 1.2f : oo / 1.2f;
        }
        o[c] = oo;
    }
    out4[idx] = make_float4(o[0], o[1], o[2], o[3]);
}

extern "C" void kernel_launch(void* const* d_in, const int* in_sizes, int n_in,
                              void* d_out, int out_size, void* d_ws, size_t ws_size,
                              hipStream_t stream) {
    const float* logits = (const float*)d_in[0];
    const int* ids = (const int*)d_in[1];
    float* out = (float*)d_out;

    float* rowThresh = (float*)((char*)d_ws + WS_ROWTHRESH);
    int* rowTie = (int*)((char*)d_ws + WS_ROWTIE);
    unsigned* gcnt = (unsigned*)((char*)d_ws + WS_GCNT);
    unsigned* mask = (unsigned*)((char*)d_ws + WS_MASK);
    uint2* gcand = (uint2*)((char*)d_ws + WS_GCAND);

    if (ws_size >= WS_NEED) {
        // fast path: zero(gcnt+mask) -> mask -> gather -> select -> apply
        zero_kernel<<<(ZERO_WORDS + 255) / 256, 256, 0, stream>>>(gcnt, ZERO_WORDS);
        build_mask_kernel<<<(B_ * L_) / 256, 256, 0, stream>>>(ids, mask);
        gather_kernel<<<GBLOCKS_G, 256, 0, stream>>>((const float4*)logits, gcand, gcnt);
        select_kernel<<<ROWS, 64, 0, stream>>>(logits, gcand, gcnt, rowThresh, rowTie);
    } else {
        zero_kernel<<<(MASK_WORDS_TOTAL + 255) / 256, 256, 0, stream>>>(mask, MASK_WORDS_TOTAL);
        build_mask_kernel<<<(B_ * L_) / 256, 256, 0, stream>>>(ids, mask);
        row_thresh_kernel<<<ROWS, RT_THREADS, 0, stream>>>(logits, rowThresh, rowTie);
    }
    apply_kernel<<<(NVEC + 255) / 256, 256, 0, stream>>>((const float4*)logits, rowThresh, rowTie,
                                                         mask, (float4*)out);
}

// Round 6
// 83.695 us; speedup vs baseline: 6.0868x; 1.5816x over previous
//
#include <hip/hip_runtime.h>
#include <stdint.h>

#define V 50257
#define B_ 64
#define S_ 8
#define ROWS (B_ * S_)
#define L_ 2048
#define NEG_INF -1000000000.0f
#define MASK_WORDS_PER_B 1571   // ceil(50257/32)
#define MASK_WORDS_TOTAL (B_ * MASK_WORDS_PER_B)   // 100544 words = 402176 B
#define TOTAL (ROWS * V)        // 25,731,584
#define NVEC (TOTAL / 4)        // 6,432,896 (exact)
#define TOP_CAP 64              // top-k=50 plus headroom for exact ties at kth
#define CAP 1024                // per-row candidate slots (expect ~128 +- 11)
#define TRAW 2.8f               // raw-value gather cutoff; P(cnt<50) ~ 1e-12/row
#define GBLK_F4 1571            // float4s per gather block (spans <= 2 rows)
#define GBLOCKS_G ((NVEC + GBLK_F4 - 1) / GBLK_F4)   // 4095
#define MASK_BLOCKS ((B_ * L_) / 256)                // 512
#define PREP_BLOCKS (MASK_BLOCKS + GBLOCKS_G)        // 4607
#define GCAP 512                // per-block LDS candidate cap (mean ~16, sd ~4)
#define GCNT_STRIDE 32          // u32s; one counter per 128-B line (no false sharing)

// ---- workspace layout ----
#define WS_ROWTHRESH 0                          // 512 f32
#define WS_ROWTIE    2048                       // 512 i32
#define WS_GCNT      4096                       // 512 counters @ 128-B stride = 65536 B
#define WS_MASK      (WS_GCNT + ROWS * GCNT_STRIDE * 4)      // 69632
#define WS_GCAND     (WS_MASK + MASK_WORDS_TOTAL * 4)        // 471808 (8-aligned)
#define WS_NEED      (WS_GCAND + (size_t)ROWS * CAP * 8)     // ~4.66 MB
// zero range covers gcnt region + mask contiguously: [WS_GCNT, WS_GCAND)
#define ZERO_WORDS   ((WS_GCAND - WS_GCNT) / 4)

__device__ __forceinline__ unsigned fkey(float f) {
    unsigned u = __float_as_uint(f);
    return (u & 0x80000000u) ? ~u : (u | 0x80000000u);
}

__device__ __forceinline__ int blockReduceSum256(int v, int tid, int* s4) {
#pragma unroll
    for (int off = 32; off; off >>= 1) v += __shfl_down(v, off);
    __syncthreads();
    if ((tid & 63) == 0) s4[tid >> 6] = v;
    __syncthreads();
    return s4[0] + s4[1] + s4[2] + s4[3];
}

__global__ __launch_bounds__(256) void zero_kernel(unsigned* __restrict__ p, int n) {
    int i = blockIdx.x * 256 + threadIdx.x;
    if (i < n) p[i] = 0u;
}

// ---------------- fused prep: mask build (blocks 0..511) + gather (rest) ----------------

// Gather blocks own float4 range [g*GBLK_F4, +GBLK_F4) — spans at most 2 rows.
// Candidates (raw v >= TRAW) buffer in LDS; at the end, <= 2 global atomicAdds
// reserve per-row ranges, then burst-write. Candidate SET per row is
// deterministic; slot order is not, but select sorts by (value, index).
__global__ __launch_bounds__(256) void prep_kernel(const float4* __restrict__ in4,
                                                   const int* __restrict__ ids,
                                                   uint2* __restrict__ gcand,
                                                   unsigned* __restrict__ gcnt,
                                                   unsigned* __restrict__ mask) {
    const int tid = threadIdx.x;
    if (blockIdx.x < MASK_BLOCKS) {
        int i = blockIdx.x * 256 + tid;           // exactly B_*L_ threads
        int t = ids[i];
        int b = i >> 11;                          // L_ = 2048
        atomicOr(&mask[b * MASK_WORDS_PER_B + (t >> 5)], 1u << (t & 31));
        return;
    }
    const int blk = blockIdx.x - MASK_BLOCKS;
    const int start = blk * GBLK_F4;
    const int end = min(start + GBLK_F4, NVEC);

    __shared__ uint2 buf[GCAP];          // (element index ee, raw value bits)
    __shared__ int lcnt, c0, base0, base1, w0, w1;
    if (tid == 0) { lcnt = 0; c0 = 0; w0 = 0; w1 = 0; }
    __syncthreads();

    for (int i = start + tid; i < end; i += 256) {
        float4 a = in4[i];
        bool p0 = a.x >= TRAW, p1 = a.y >= TRAW, p2 = a.z >= TRAW, p3 = a.w >= TRAW;
        if (p0 | p1 | p2 | p3) {
            unsigned e = (unsigned)i << 2;
            if (p0) { int p = atomicAdd(&lcnt, 1); if (p < GCAP) buf[p] = make_uint2(e,      __float_as_uint(a.x)); }
            if (p1) { int p = atomicAdd(&lcnt, 1); if (p < GCAP) buf[p] = make_uint2(e + 1u, __float_as_uint(a.y)); }
            if (p2) { int p = atomicAdd(&lcnt, 1); if (p < GCAP) buf[p] = make_uint2(e + 2u, __float_as_uint(a.z)); }
            if (p3) { int p = atomicAdd(&lcnt, 1); if (p < GCAP) buf[p] = make_uint2(e + 3u, __float_as_uint(a.w)); }
        }
    }
    __syncthreads();

    const int cnt = lcnt;
    const int take = cnt < GCAP ? cnt : GCAP;
    const unsigned rlo = (unsigned)(((size_t)start * 4) / V);
    const unsigned rhi = (unsigned)(((size_t)end * 4 - 1) / V);

    for (int j = tid; j < take; j += 256)
        if (buf[j].x / (unsigned)V == rlo) atomicAdd(&c0, 1);
    __syncthreads();

    if (tid == 0) {
        base0 = (int)atomicAdd(&gcnt[rlo * GCNT_STRIDE], (unsigned)c0);
        int c1 = take - c0;
        base1 = (c1 > 0) ? (int)atomicAdd(&gcnt[rhi * GCNT_STRIDE], (unsigned)c1) : 0;
        if (cnt > GCAP) {   // LDS overflow (never on this data): force exact fallback
            atomicAdd(&gcnt[rlo * GCNT_STRIDE], 1000000u);
            atomicAdd(&gcnt[rhi * GCNT_STRIDE], 1000000u);
        }
    }
    __syncthreads();

    for (int j = tid; j < take; j += 256) {
        unsigned ee = buf[j].x, vb = buf[j].y;
        unsigned r = ee / (unsigned)V;
        unsigned tok = ee - r * (unsigned)V;
        int p = (r == rlo) ? base0 + atomicAdd(&w0, 1) : base1 + atomicAdd(&w1, 1);
        if (p < CAP) gcand[((size_t)r << 10) + p] = make_uint2(vb, tok);
    }
}

// One 256-thread block per row. Parallel rank-sort (no serial extract-max).
// Exact reference semantics incl. fp32 ties: kth = 50th largest of x=v/0.8;
// kept = ALL x >= kth; stable (value desc, index asc) order like
// np.argsort(-x); f64 softmax+cumsum decision.
__global__ __launch_bounds__(256) void select_kernel(const float* __restrict__ logits,
                                                     const uint2* __restrict__ gcand,
                                                     const unsigned* __restrict__ gcnt,
                                                     float* __restrict__ rowThresh,
                                                     int* __restrict__ rowTie) {
    const int row = blockIdx.x;
    const int tid = threadIdx.x;
    __shared__ uint2 cvi[CAP];           // (x bits, token idx)
    __shared__ float sVal[TOP_CAP];
    __shared__ int   sIdx[TOP_CAP];
    __shared__ double sExp[TOP_CAP];
    __shared__ int s_c, s_M;
    __shared__ int s_red[4];

    int cnt = (int)gcnt[row * GCNT_STRIDE];
    const float* rp = logits + (size_t)row * V;

    if (cnt >= 50 && cnt <= CAP) {
        for (int j = tid; j < cnt; j += 256) {
            uint2 u = gcand[((size_t)row << 10) + j];
            cvi[j] = make_uint2(__float_as_uint(__uint_as_float(u.x) / 0.8f), u.y);
        }
    } else {
        // Pathological-only fallback: exact bisect in raw key space for the
        // 50th-largest, then re-gather with 2-ulp slack (covers /0.8 merging
        // distinct raw values into equal x).
        unsigned lo = 0u, hi = 0xFFFFFFFFu;
        while (lo < hi) {
            unsigned mid = lo + ((hi - lo) >> 1) + 1u;
            int c = 0;
            for (int j = tid; j < V; j += 256) c += (int)(fkey(rp[j]) >= mid);
            c = blockReduceSum256(c, tid, s_red);
            if (c >= 50) lo = mid; else hi = mid - 1u;
        }
        unsigned gl = (lo > 2u) ? lo - 2u : 0u;
        if (tid == 0) s_c = 0;
        __syncthreads();
        for (int j = tid; j < V; j += 256) {
            float v = rp[j];
            if (fkey(v) >= gl) {
                int p = atomicAdd(&s_c, 1);
                if (p < CAP) cvi[p] = make_uint2(__float_as_uint(v / 0.8f), (unsigned)j);
            }
        }
        __syncthreads();
        cnt = s_c < CAP ? s_c : CAP;
    }
    if (tid < TOP_CAP) { sVal[tid] = -3.4e38f; sIdx[tid] = 0x7FFFFFFF; }
    __syncthreads();

    // Rank-sort: each thread owns up to 4 candidates (CAP/256); the j-loop is
    // an LDS broadcast read (all lanes same address -> conflict-free). Ranks
    // are unique via the (value desc, token idx asc) key.
    {
        float v0 = -3.4e38f, v1 = -3.4e38f, v2 = -3.4e38f, v3 = -3.4e38f;
        int i0 = 0x7FFFFFFF, i1 = 0x7FFFFFFF, i2 = 0x7FFFFFFF, i3 = 0x7FFFFFFF;
        if (tid < cnt)       { uint2 u = cvi[tid];       v0 = __uint_as_float(u.x); i0 = (int)u.y; }
        if (tid + 256 < cnt) { uint2 u = cvi[tid + 256]; v1 = __uint_as_float(u.x); i1 = (int)u.y; }
        if (tid + 512 < cnt) { uint2 u = cvi[tid + 512]; v2 = __uint_as_float(u.x); i2 = (int)u.y; }
        if (tid + 768 < cnt) { uint2 u = cvi[tid + 768]; v3 = __uint_as_float(u.x); i3 = (int)u.y; }
        int r0 = 0, r1 = 0, r2 = 0, r3 = 0;
        for (int j = 0; j < cnt; ++j) {
            uint2 u = cvi[j];
            float w = __uint_as_float(u.x);
            int wi = (int)u.y;
            r0 += (w > v0) || (w == v0 && wi < i0);
            r1 += (w > v1) || (w == v1 && wi < i1);
            r2 += (w > v2) || (w == v2 && wi < i2);
            r3 += (w > v3) || (w == v3 && wi < i3);
        }
        if (tid < cnt && r0 < TOP_CAP)       { sVal[r0] = v0; sIdx[r0] = i0; }
        if (tid + 256 < cnt && r1 < TOP_CAP) { sVal[r1] = v1; sIdx[r1] = i1; }
        if (tid + 512 < cnt && r2 < TOP_CAP) { sVal[r2] = v2; sIdx[r2] = i2; }
        if (tid + 768 < cnt && r3 < TOP_CAP) { sVal[r3] = v3; sIdx[r3] = i3; }
    }
    __syncthreads();

    if (tid == 0) {
        float kth = sVal[49];
        int M = 50;
        while (M < TOP_CAP && sVal[M] == kth) ++M;   // include exact ties at kth
        s_M = M;
    }
    __syncthreads();
    int M = s_M;
    if (tid < M) sExp[tid] = exp((double)sVal[tid] - (double)sVal[0]);
    __syncthreads();
    if (tid == 0) {
        double denom = 0.0;
        for (int i = 0; i < M; ++i) denom += sExp[i];
        double cum = 0.0;
        int J = M - 1;
        for (int i = 0; i < M; ++i) {
            cum += sExp[i] / denom;
            if (cum > 0.9) { J = i; break; }
        }
        rowThresh[row] = sVal[J];
        rowTie[row] = sIdx[J];   // among x == thresh, keep token index <= this
    }
}

// ---------------- safety fallback path (round-3 kernel, ws too small) ----------------
#define CAND_CAP 4096
#define FIN_CAP 1024
#define RT_THREADS 1024

__device__ __forceinline__ int blockReduceSum(int v, int tid, int* s16) {
#pragma unroll
    for (int off = 32; off; off >>= 1) v += __shfl_down(v, off);
    __syncthreads();
    if ((tid & 63) == 0) s16[tid >> 6] = v;
    __syncthreads();
    int t = 0;
#pragma unroll
    for (int k = 0; k < RT_THREADS / 64; ++k) t += s16[k];
    return t;
}

__global__ __launch_bounds__(RT_THREADS, 8) void row_thresh_kernel(
        const float* __restrict__ logits, float* __restrict__ rowThresh,
        int* __restrict__ rowTie) {
    const int tid = threadIdx.x;
    const int row = blockIdx.x;
    if (row >= ROWS) return;
    const float* rp = logits + (size_t)row * V;

    __shared__ float candV[CAND_CAP];
    __shared__ int   candI[CAND_CAP];
    __shared__ float finV[FIN_CAP];
    __shared__ int   finI[FIN_CAP];
    __shared__ float sVal[TOP_CAP];
    __shared__ int   sIdx[TOP_CAP];
    __shared__ double sExp[TOP_CAP];
    __shared__ int s_cnt, s_M;
    __shared__ int s_red[RT_THREADS / 64];

    const unsigned mis = (unsigned)(((size_t)row * (size_t)V) & 3u);
    const int a0 = (int)((4u - mis) & 3u);
    const int nv = (V - a0) >> 2;
    const int tailStart = a0 + (nv << 2);
    const float4* vp = reinterpret_cast<const float4*>(rp + a0);

    float TR = 2.4f;
    int cnt = 0;
    for (int attempt = 0; attempt < 12; ++attempt) {
        if (tid == 0) s_cnt = 0;
        __syncthreads();
        for (int base = tid; base < nv; base += 4 * RT_THREADS) {
            int i1 = base + RT_THREADS, i2 = base + 2 * RT_THREADS, i3 = base + 3 * RT_THREADS;
            float4 a = vp[base];
            float4 b = vp[i1 < nv ? i1 : nv - 1];
            float4 c = vp[i2 < nv ? i2 : nv - 1];
            float4 d = vp[i3 < nv ? i3 : nv - 1];
            float va[16] = {a.x, a.y, a.z, a.w, b.x, b.y, b.z, b.w,
                            c.x, c.y, c.z, c.w, d.x, d.y, d.z, d.w};
            int ib[4] = {base, i1, i2, i3};
            bool ok[4] = {true, i1 < nv, i2 < nv, i3 < nv};
#pragma unroll
            for (int q = 0; q < 4; ++q) {
                if (!ok[q]) continue;
#pragma unroll
                for (int cc = 0; cc < 4; ++cc) {
                    float v = va[q * 4 + cc];
                    if (v >= TR) {
                        int p = atomicAdd(&s_cnt, 1);
                        if (p < CAND_CAP) { candV[p] = v / 0.8f; candI[p] = a0 + (ib[q] << 2) + cc; }
                    }
                }
            }
        }
        if (tid < a0) {
            float v = rp[tid];
            if (v >= TR) {
                int p = atomicAdd(&s_cnt, 1);
                if (p < CAND_CAP) { candV[p] = v / 0.8f; candI[p] = tid; }
            }
        }
        if (tid < V - tailStart) {
            float v = rp[tailStart + tid];
            if (v >= TR) {
                int p = atomicAdd(&s_cnt, 1);
                if (p < CAND_CAP) { candV[p] = v / 0.8f; candI[p] = tailStart + tid; }
            }
        }
        __syncthreads();
        cnt = s_cnt;
        if (cnt >= 50 && cnt <= CAND_CAP) break;
        if (cnt < 50) TR -= 1.2f; else TR += 1.2f;
        __syncthreads();
    }
    if (cnt > CAND_CAP) cnt = CAND_CAP;

    const float* fV;
    const int* fI;
    int F;
    if (cnt <= FIN_CAP) {
        fV = candV; fI = candI; F = cnt;
    } else {
        unsigned lo = fkey(TR / 0.8f) - 1u;
        unsigned hi = 0xFFFFFFFFu;
        while (lo < hi) {
            unsigned mid = lo + ((hi - lo) >> 1) + 1u;
            int c = 0;
            for (int i = tid; i < cnt; i += RT_THREADS) c += (int)(fkey(candV[i]) >= mid);
            c = blockReduceSum(c, tid, s_red);
            if (c >= 50) lo = mid; else hi = mid - 1u;
        }
        __syncthreads();
        if (tid == 0) s_cnt = 0;
        __syncthreads();
        for (int i = tid; i < cnt; i += RT_THREADS) {
            if (fkey(candV[i]) >= lo) {
                int p = atomicAdd(&s_cnt, 1);
                if (p < FIN_CAP) { finV[p] = candV[i]; finI[p] = candI[i]; }
            }
        }
        __syncthreads();
        F = s_cnt < FIN_CAP ? s_cnt : FIN_CAP;
        fV = finV; fI = finI;
    }

    if (tid < TOP_CAP) { sVal[tid] = -3.4e38f; sIdx[tid] = 0x7FFFFFFF; }
    __syncthreads();

    {
        float v0 = (tid < F) ? fV[tid] : -3.4e38f;
        int i0 = (tid < F) ? fI[tid] : 0x7FFFFFFF;
        int r0 = 0;
        for (int j = 0; j < F; ++j) {
            float w = fV[j];
            int wi = fI[j];
            r0 += (w > v0) || (w == v0 && wi < i0);
        }
        if (tid < F && r0 < TOP_CAP) { sVal[r0] = v0; sIdx[r0] = i0; }
    }
    __syncthreads();

    if (tid == 0) {
        float kth = sVal[49];
        int M = 50;
        while (M < TOP_CAP && sVal[M] == kth) ++M;
        s_M = M;
    }
    __syncthreads();
    int M = s_M;
    if (tid < M) sExp[tid] = exp((double)sVal[tid] - (double)sVal[0]);
    __syncthreads();

    if (tid == 0) {
        double denom = 0.0;
#pragma unroll 1
        for (int i = 0; i < M; ++i) denom += sExp[i];
        double cum = 0.0;
        int J = M - 1;
#pragma unroll 1
        for (int i = 0; i < M; ++i) {
            cum += sExp[i] / denom;
            if (cum > 0.9) { J = i; break; }
        }
        rowThresh[row] = sVal[J];
        rowTie[row] = sIdx[J];
    }
}

__global__ __launch_bounds__(256) void build_mask_kernel(const int* __restrict__ ids,
                                                         unsigned* __restrict__ mask) {
    int i = blockIdx.x * 256 + threadIdx.x;
    if (i >= B_ * L_) return;
    int t = ids[i];
    int b = i >> 11;
    atomicOr(&mask[b * MASK_WORDS_PER_B + (t >> 5)], 1u << (t & 31));
}

// ---------------- apply ----------------

__global__ __launch_bounds__(256) void apply_kernel(const float4* __restrict__ in4,
                                                    const float* __restrict__ rowThresh,
                                                    const int* __restrict__ rowTie,
                                                    const unsigned* __restrict__ mask,
                                                    float4* __restrict__ out4) {
    int idx = blockIdx.x * 256 + threadIdx.x;
    if (idx >= NVEC) return;
    unsigned e = (unsigned)idx << 2;
    unsigned row = e / (unsigned)V;
    unsigned rem = e - row * (unsigned)V;
    float4 v = in4[idx];
    float xs[4] = {v.x, v.y, v.z, v.w};
    float o[4];
    float t0 = rowThresh[row];
    int ti0 = rowTie[row];
    bool crosses = (rem + 3u >= (unsigned)V);
    float t1 = crosses ? rowThresh[row + 1] : t0;
    int ti1 = crosses ? rowTie[row + 1] : ti0;
#pragma unroll
    for (int c = 0; c < 4; ++c) {
        unsigned tok = rem + (unsigned)c;
        unsigned r = row;
        float t = t0;
        int ti = ti0;
        if (tok >= (unsigned)V) { tok -= (unsigned)V; r = row + 1u; t = t1; ti = ti1; }
        float x = xs[c] / 0.8f;
        bool keep = (x > t) || (x == t && (int)tok <= ti);
        float oo = keep ? x : NEG_INF;
        if ((r & 7u) == 7u) {
            unsigned w = mask[(r >> 3) * MASK_WORDS_PER_B + (tok >> 5)];
            if ((w >> (tok & 31u)) & 1u) oo = (oo < 0.0f) ? oo * 1.2f : oo / 1.2f;
        }
        o[c] = oo;
    }
    out4[idx] = make_float4(o[0], o[1], o[2], o[3]);
}

extern "C" void kernel_launch(void* const* d_in, const int* in_sizes, int n_in,
                              void* d_out, int out_size, void* d_ws, size_t ws_size,
                              hipStream_t stream) {
    const float* logits = (const float*)d_in[0];
    const int* ids = (const int*)d_in[1];
    float* out = (float*)d_out;

    float* rowThresh = (float*)((char*)d_ws + WS_ROWTHRESH);
    int* rowTie = (int*)((char*)d_ws + WS_ROWTIE);
    unsigned* gcnt = (unsigned*)((char*)d_ws + WS_GCNT);
    unsigned* mask = (unsigned*)((char*)d_ws + WS_MASK);
    uint2* gcand = (uint2*)((char*)d_ws + WS_GCAND);

    if (ws_size >= WS_NEED) {
        // fast path: zero(gcnt+mask) -> prep(mask+gather fused) -> select -> apply
        zero_kernel<<<(ZERO_WORDS + 255) / 256, 256, 0, stream>>>(gcnt, ZERO_WORDS);
        prep_kernel<<<PREP_BLOCKS, 256, 0, stream>>>((const float4*)logits, ids, gcand, gcnt, mask);
        select_kernel<<<ROWS, 256, 0, stream>>>(logits, gcand, gcnt, rowThresh, rowTie);
    } else {
        zero_kernel<<<(MASK_WORDS_TOTAL + 255) / 256, 256, 0, stream>>>(mask, MASK_WORDS_TOTAL);
        build_mask_kernel<<<(B_ * L_) / 256, 256, 0, stream>>>(ids, mask);
        row_thresh_kernel<<<ROWS, RT_THREADS, 0, stream>>>(logits, rowThresh, rowTie);
    }
    apply_kernel<<<(NVEC + 255) / 256, 256, 0, stream>>>((const float4*)logits, rowThresh, rowTie,
                                                         mask, (float4*)out);
}

// Round 7
// 75.344 us; speedup vs baseline: 6.7615x; 1.1108x over previous
//
#include <hip/hip_runtime.h>
#include <stdint.h>

#define V 50257
#define B_ 64
#define S_ 8
#define ROWS (B_ * S_)
#define L_ 2048
#define NEG_INF -1000000000.0f
#define MASK_WORDS_PER_B 1571   // ceil(50257/32)
#define MASK_WORDS_TOTAL (B_ * MASK_WORDS_PER_B)   // 100544 words = 402176 B
#define TOTAL (ROWS * V)        // 25,731,584
#define NVEC (TOTAL / 4)        // 6,432,896 (exact)
#define TOP_CAP 64              // top-k=50 plus headroom for exact ties at kth
#define TRAW 2.8f               // raw-value gather cutoff; E[cnt]=128, P(cnt<50)~1e-12
#define GBLK_F4 1571            // float4s per gather block (spans <= 2 rows)
#define GBLOCKS_G ((NVEC + GBLK_F4 - 1) / GBLK_F4)   // 4095
#define PREP_BLOCKS (B_ + GBLOCKS_G)                 // 64 mask + 4095 gather
#define GCAP_BLK 64             // per-block candidate region (mean 16, sd 4 -> 12 sigma)
#define CAPROW 512              // per-row candidate cap in select

// ---- workspace layout (no pre-zeroing needed anywhere) ----
#define WS_ROWPARAM 0                                   // 512 * 16 B = 8192
#define WS_BCNT     8192                                // 4095 u32 -> pad 16384
#define WS_MASK     (WS_BCNT + 16384)                   // 24576; 402176 B
#define WS_GCAND    (WS_MASK + MASK_WORDS_TOTAL * 4)    // 426752 (8-aligned)
#define WS_NEED     (WS_GCAND + (size_t)GBLOCKS_G * GCAP_BLK * 8)   // ~2.5 MB

__device__ __forceinline__ unsigned fkey(float f) {
    unsigned u = __float_as_uint(f);
    return (u & 0x80000000u) ? ~u : (u | 0x80000000u);
}

__device__ __forceinline__ int blockReduceSum256(int v, int tid, int* s4) {
#pragma unroll
    for (int off = 32; off; off >>= 1) v += __shfl_down(v, off);
    __syncthreads();
    if ((tid & 63) == 0) s4[tid >> 6] = v;
    __syncthreads();
    return s4[0] + s4[1] + s4[2] + s4[3];
}

// ---------------- prep: LDS mask build (blocks 0..63) + private-region gather ----------------

__global__ __launch_bounds__(256) void prep_kernel(const float4* __restrict__ in4,
                                                   const int* __restrict__ ids,
                                                   uint2* __restrict__ gcand,
                                                   unsigned* __restrict__ bcnt,
                                                   unsigned* __restrict__ mask) {
    const int tid = threadIdx.x;
    __shared__ alignas(16) unsigned lds[MASK_WORDS_PER_B];
    __shared__ int lcnt;

    if (blockIdx.x < B_) {
        // presence bitmask for batch b, built in LDS (no global zero, no global atomics)
        const int b = blockIdx.x;
        for (int w = tid; w < MASK_WORDS_PER_B; w += 256) lds[w] = 0u;
        __syncthreads();
        const int* bp = ids + b * L_;
#pragma unroll
        for (int k = 0; k < L_ / 256; ++k) {
            int t = bp[k * 256 + tid];
            atomicOr(&lds[t >> 5], 1u << (t & 31));
        }
        __syncthreads();
        unsigned* mp = mask + b * MASK_WORDS_PER_B;
        for (int w = tid; w < MASK_WORDS_PER_B; w += 256) mp[w] = lds[w];
        return;
    }

    // gather block: owns f4 range [start,end), writes its PRIVATE gcand region +
    // a plain count store. Candidate SET deterministic; slot order canonicalized
    // by select's (value, index) sort.
    const int blk = blockIdx.x - B_;
    const int start = blk * GBLK_F4;
    const int end = min(start + GBLK_F4, NVEC);
    uint2* buf = (uint2*)lds;            // 64 entries, aliases mask LDS
    if (tid == 0) lcnt = 0;
    __syncthreads();

    float4 va[7];                        // 7*256 = 1792 >= 1571: unconditional clamped loads (MLP)
#pragma unroll
    for (int k = 0; k < 7; ++k) {
        int i = start + tid + k * 256;
        va[k] = in4[min(i, NVEC - 1)];
    }
#pragma unroll
    for (int k = 0; k < 7; ++k) {
        int i = start + tid + k * 256;
        if (i < end) {
            float4 a = va[k];
            unsigned e = (unsigned)i << 2;
            if (a.x >= TRAW) { int p = atomicAdd(&lcnt, 1); if (p < GCAP_BLK) buf[p] = make_uint2(e,      __float_as_uint(a.x)); }
            if (a.y >= TRAW) { int p = atomicAdd(&lcnt, 1); if (p < GCAP_BLK) buf[p] = make_uint2(e + 1u, __float_as_uint(a.y)); }
            if (a.z >= TRAW) { int p = atomicAdd(&lcnt, 1); if (p < GCAP_BLK) buf[p] = make_uint2(e + 2u, __float_as_uint(a.z)); }
            if (a.w >= TRAW) { int p = atomicAdd(&lcnt, 1); if (p < GCAP_BLK) buf[p] = make_uint2(e + 3u, __float_as_uint(a.w)); }
        }
    }
    __syncthreads();
    if (tid == 0) bcnt[blk] = (unsigned)lcnt;   // actual count; >GCAP_BLK flags overflow
    int take = min(lcnt, GCAP_BLK);
    for (int j = tid; j < take; j += 256) gcand[(size_t)blk * GCAP_BLK + j] = buf[j];
}

// ---------------- select: per-row exact threshold -> raw-space bounds ----------------

// One 256-thread block per row. Exact reference semantics incl. fp32 ties:
// kth = 50th largest of x=v/0.8f; kept = ALL x >= kth; stable (x desc, idx asc)
// order like np.argsort(-x); f64 softmax+cumsum decision. Emits rowParam =
// {vlo, vhi, tie}: raw preimage of threshold x-value + positional tie-break.
__global__ __launch_bounds__(256) void select_kernel(const float* __restrict__ logits,
                                                     const uint2* __restrict__ gcand,
                                                     const unsigned* __restrict__ bcnt,
                                                     uint4* __restrict__ rowParam) {
    const int row = blockIdx.x;
    const int tid = threadIdx.x;
    __shared__ float cX[CAPROW];
    __shared__ unsigned cR[CAPROW];
    __shared__ int cI[CAPROW];
    __shared__ float sVal[TOP_CAP];
    __shared__ int sIdx[TOP_CAP];
    __shared__ double sExp[TOP_CAP];
    __shared__ int s_c, s_M, s_bad, s_ti;
    __shared__ float s_t;
    __shared__ unsigned s_lo, s_hi;
    __shared__ int s_red[4];

    const float* rp = logits + (size_t)row * V;
    const unsigned e0 = (unsigned)row * (unsigned)V;
    if (tid == 0) { s_c = 0; s_bad = 0; }
    __syncthreads();

    {   // scan the <=9 gather-block regions overlapping this row; filter by row
        const int b0 = (int)((e0 >> 2) / GBLK_F4);
        const int b1 = (int)(((e0 + V - 1) >> 2) / GBLK_F4);
        for (int blk = b0; blk <= b1; ++blk) {
            unsigned c = bcnt[blk];
            if (c > GCAP_BLK && tid == 0) s_bad = 1;
            int take = min((int)c, GCAP_BLK);
            for (int j = tid; j < take; j += 256) {
                uint2 u = gcand[(size_t)blk * GCAP_BLK + j];
                if (u.x / (unsigned)V == (unsigned)row) {
                    int p = atomicAdd(&s_c, 1);
                    if (p < CAPROW) {
                        cR[p] = u.y;
                        cX[p] = __uint_as_float(u.y) / 0.8f;
                        cI[p] = (int)(u.x - e0);
                    }
                }
            }
        }
    }
    __syncthreads();
    int cnt = s_c;
    if (s_bad || cnt < 50 || cnt > CAPROW) {
        // Pathological-only exact fallback: bisect raw key space for the 50th
        // largest, re-gather with 2-ulp slack (covers /0.8 merging distinct raws).
        unsigned lo = 0u, hi = 0xFFFFFFFFu;
        while (lo < hi) {
            unsigned mid = lo + ((hi - lo) >> 1) + 1u;
            int c = 0;
            for (int j = tid; j < V; j += 256) c += (int)(fkey(rp[j]) >= mid);
            c = blockReduceSum256(c, tid, s_red);
            if (c >= 50) lo = mid; else hi = mid - 1u;
        }
        unsigned gl = (lo > 2u) ? lo - 2u : 0u;
        __syncthreads();
        if (tid == 0) s_c = 0;
        __syncthreads();
        for (int j = tid; j < V; j += 256) {
            float v = rp[j];
            if (fkey(v) >= gl) {
                int p = atomicAdd(&s_c, 1);
                if (p < CAPROW) { cR[p] = __float_as_uint(v); cX[p] = v / 0.8f; cI[p] = j; }
            }
        }
        __syncthreads();
        cnt = min(s_c, CAPROW);
    }

    if (tid < TOP_CAP) { sVal[tid] = -3.4e38f; sIdx[tid] = 0x7FFFFFFF; }
    __syncthreads();

    // Rank-sort: each thread owns <=2 candidates; j-loop is an LDS broadcast
    // read (conflict-free). Ranks unique via (x desc, token idx asc) key.
    {
        float v0 = -3.4e38f, v1 = -3.4e38f;
        int i0 = 0x7FFFFFFF, i1 = 0x7FFFFFFF;
        if (tid < cnt) { v0 = cX[tid]; i0 = cI[tid]; }
        if (tid + 256 < cnt) { v1 = cX[tid + 256]; i1 = cI[tid + 256]; }
        int r0 = 0, r1 = 0;
        for (int j = 0; j < cnt; ++j) {
            float w = cX[j];
            int wi = cI[j];
            r0 += (w > v0) || (w == v0 && wi < i0);
            r1 += (w > v1) || (w == v1 && wi < i1);
        }
        if (tid < cnt && r0 < TOP_CAP) { sVal[r0] = v0; sIdx[r0] = i0; }
        if (tid + 256 < cnt && r1 < TOP_CAP) { sVal[r1] = v1; sIdx[r1] = i1; }
    }
    __syncthreads();

    if (tid == 0) {
        float kth = sVal[49];
        int M = 50;
        while (M < TOP_CAP && sVal[M] == kth) ++M;   // include exact ties at kth
        s_M = M;
    }
    __syncthreads();
    int M = s_M;
    if (tid < M) sExp[tid] = exp((double)sVal[tid] - (double)sVal[0]);
    __syncthreads();
    if (tid == 0) {
        double denom = 0.0;
        for (int i = 0; i < M; ++i) denom += sExp[i];
        double cum = 0.0;
        int J = M - 1;
        for (int i = 0; i < M; ++i) {
            cum += sExp[i] / denom;
            if (cum > 0.9) { J = i; break; }
        }
        s_t = sVal[J];
        s_ti = sIdx[J];
        s_lo = 0xFFFFFFFFu;
        s_hi = 0u;
    }
    __syncthreads();
    // raw preimage of x==t among candidates (all row tokens with x==t are
    // candidates since t >= 3.5 > TRAW/0.8); positive floats -> uint order ok
    float t = s_t;
    for (int j = tid; j < cnt; j += 256) {
        if (cX[j] == t) { atomicMin(&s_lo, cR[j]); atomicMax(&s_hi, cR[j]); }
    }
    __syncthreads();
    if (tid == 0) rowParam[row] = make_uint4(s_lo, s_hi, (unsigned)s_ti, 0u);
}

// ---------------- apply: raw-space decision, no divides ----------------

__global__ __launch_bounds__(256) void apply_kernel(const float4* __restrict__ in4,
                                                    const uint4* __restrict__ rowParam,
                                                    const unsigned* __restrict__ mask,
                                                    float4* __restrict__ out4) {
    int gid = blockIdx.x * 256 + threadIdx.x;
    int i0 = gid << 1;                      // two consecutive float4s (NVEC even)
    if (i0 >= NVEC) return;
    float4 a = in4[i0];
    float4 b = in4[i0 + 1];
    unsigned e = (unsigned)i0 << 2;
    unsigned row = e / (unsigned)V;         // magic-mul
    unsigned tok0 = e - row * (unsigned)V;
    uint4 p0 = rowParam[row];
    bool crosses = (tok0 + 7u >= (unsigned)V);   // never true in last row
    uint4 p1 = crosses ? rowParam[row + 1] : p0;
    float xs[8] = {a.x, a.y, a.z, a.w, b.x, b.y, b.z, b.w};
    float o[8];
#pragma unroll
    for (int c = 0; c < 8; ++c) {
        unsigned tok = tok0 + (unsigned)c;
        unsigned r = row;
        uint4 pp = p0;
        if (tok >= (unsigned)V) { tok -= (unsigned)V; r = row + 1u; pp = p1; }
        float v = xs[c];
        float vlo = __uint_as_float(pp.x);
        float vhi = __uint_as_float(pp.y);
        // exact keep decision: x(v) > t  <=>  v > vhi ; x(v) == t <=> v in [vlo,vhi]
        bool keep = (v > vhi) || (v >= vlo && tok <= pp.z);
        float oo = keep ? v * 1.25f : NEG_INF;   // <=1 ulp from v/0.8f (tol 2.4e7)
        if ((r & 7u) == 7u) {
            unsigned w = mask[(r >> 3) * MASK_WORDS_PER_B + (tok >> 5)];
            if ((w >> (tok & 31u)) & 1u) oo = (oo < 0.0f) ? oo * 1.2f : oo * (1.0f / 1.2f);
        }
        o[c] = oo;
    }
    out4[i0] = make_float4(o[0], o[1], o[2], o[3]);
    out4[i0 + 1] = make_float4(o[4], o[5], o[6], o[7]);
}

// ---------------- safety fallback (ws too small; never expected) ----------------
#define CAND_CAP 4096
#define RT_THREADS 1024

__global__ __launch_bounds__(256) void mask_only_kernel(const int* __restrict__ ids,
                                                        unsigned* __restrict__ mask) {
    const int tid = threadIdx.x;
    const int b = blockIdx.x;
    __shared__ unsigned lds[MASK_WORDS_PER_B];
    for (int w = tid; w < MASK_WORDS_PER_B; w += 256) lds[w] = 0u;
    __syncthreads();
    const int* bp = ids + b * L_;
#pragma unroll
    for (int k = 0; k < L_ / 256; ++k) {
        int t = bp[k * 256 + tid];
        atomicOr(&lds[t >> 5], 1u << (t & 31));
    }
    __syncthreads();
    unsigned* mp = mask + b * MASK_WORDS_PER_B;
    for (int w = tid; w < MASK_WORDS_PER_B; w += 256) mp[w] = lds[w];
}

__device__ __forceinline__ int blockReduceSum1024(int v, int tid, int* s16) {
#pragma unroll
    for (int off = 32; off; off >>= 1) v += __shfl_down(v, off);
    __syncthreads();
    if ((tid & 63) == 0) s16[tid >> 6] = v;
    __syncthreads();
    int t = 0;
#pragma unroll
    for (int k = 0; k < RT_THREADS / 64; ++k) t += s16[k];
    return t;
}

__global__ __launch_bounds__(RT_THREADS, 8) void row_thresh_kernel(
        const float* __restrict__ logits, uint4* __restrict__ rowParam) {
    const int tid = threadIdx.x;
    const int row = blockIdx.x;
    if (row >= ROWS) return;
    const float* rp = logits + (size_t)row * V;

    __shared__ float candV[CAND_CAP];
    __shared__ int   candI[CAND_CAP];
    __shared__ float sVal[TOP_CAP];
    __shared__ int   sIdx[TOP_CAP];
    __shared__ double sExp[TOP_CAP];
    __shared__ int s_cnt, s_M;
    __shared__ int s_red[RT_THREADS / 64];

    const unsigned mis = (unsigned)(((size_t)row * (size_t)V) & 3u);
    const int a0 = (int)((4u - mis) & 3u);
    const int nv = (V - a0) >> 2;
    const int tailStart = a0 + (nv << 2);
    const float4* vp = reinterpret_cast<const float4*>(rp + a0);

    float TR = 2.4f;
    int cnt = 0;
    for (int attempt = 0; attempt < 12; ++attempt) {
        if (tid == 0) s_cnt = 0;
        __syncthreads();
        for (int base = tid; base < nv; base += 4 * RT_THREADS) {
            int i1 = base + RT_THREADS, i2 = base + 2 * RT_THREADS, i3 = base + 3 * RT_THREADS;
            float4 a = vp[base];
            float4 b = vp[i1 < nv ? i1 : nv - 1];
            float4 c = vp[i2 < nv ? i2 : nv - 1];
            float4 d = vp[i3 < nv ? i3 : nv - 1];
            float va[16] = {a.x, a.y, a.z, a.w, b.x, b.y, b.z, b.w,
                            c.x, c.y, c.z, c.w, d.x, d.y, d.z, d.w};
            int ib[4] = {base, i1, i2, i3};
            bool ok[4] = {true, i1 < nv, i2 < nv, i3 < nv};
#pragma unroll
            for (int q = 0; q < 4; ++q) {
                if (!ok[q]) continue;
#pragma unroll
                for (int cc = 0; cc < 4; ++cc) {
                    float v = va[q * 4 + cc];
                    if (v >= TR) {
                        int p = atomicAdd(&s_cnt, 1);
                        if (p < CAND_CAP) { candV[p] = v / 0.8f; candI[p] = a0 + (ib[q] << 2) + cc; }
                    }
                }
            }
        }
        if (tid < a0) {
            float v = rp[tid];
            if (v >= TR) {
                int p = atomicAdd(&s_cnt, 1);
                if (p < CAND_CAP) { candV[p] = v / 0.8f; candI[p] = tid; }
            }
        }
        if (tid < V - tailStart) {
            float v = rp[tailStart + tid];
            if (v >= TR) {
                int p = atomicAdd(&s_cnt, 1);
                if (p < CAND_CAP) { candV[p] = v / 0.8f; candI[p] = tailStart + tid; }
            }
        }
        __syncthreads();
        cnt = s_cnt;
        if (cnt >= 50 && cnt <= CAND_CAP) break;
        if (cnt < 50) TR -= 1.2f; else TR += 1.2f;
        __syncthreads();
    }
    if (cnt > CAND_CAP) cnt = CAND_CAP;

    if (tid < TOP_CAP) { sVal[tid] = -3.4e38f; sIdx[tid] = 0x7FFFFFFF; }
    __syncthreads();

    {
        float v0 = (tid < cnt) ? candV[tid] : -3.4e38f;
        int i0 = (tid < cnt) ? candI[tid] : 0x7FFFFFFF;
        float v1 = (tid + RT_THREADS < cnt) ? candV[tid + RT_THREADS] : -3.4e38f;
        int i1 = (tid + RT_THREADS < cnt) ? candI[tid + RT_THREADS] : 0x7FFFFFFF;
        float v2 = (tid + 2 * RT_THREADS < cnt) ? candV[tid + 2 * RT_THREADS] : -3.4e38f;
        int i2 = (tid + 2 * RT_THREADS < cnt) ? candI[tid + 2 * RT_THREADS] : 0x7FFFFFFF;
        float v3 = (tid + 3 * RT_THREADS < cnt) ? candV[tid + 3 * RT_THREADS] : -3.4e38f;
        int i3 = (tid + 3 * RT_THREADS < cnt) ? candI[tid + 3 * RT_THREADS] : 0x7FFFFFFF;
        int r0 = 0, r1 = 0, r2 = 0, r3 = 0;
        for (int j = 0; j < cnt; ++j) {
            float w = candV[j];
            int wi = candI[j];
            r0 += (w > v0) || (w == v0 && wi < i0);
            r1 += (w > v1) || (w == v1 && wi < i1);
            r2 += (w > v2) || (w == v2 && wi < i2);
            r3 += (w > v3) || (w == v3 && wi < i3);
        }
        if (tid < cnt && r0 < TOP_CAP) { sVal[r0] = v0; sIdx[r0] = i0; }
        if (tid + RT_THREADS < cnt && r1 < TOP_CAP) { sVal[r1] = v1; sIdx[r1] = i1; }
        if (tid + 2 * RT_THREADS < cnt && r2 < TOP_CAP) { sVal[r2] = v2; sIdx[r2] = i2; }
        if (tid + 3 * RT_THREADS < cnt && r3 < TOP_CAP) { sVal[r3] = v3; sIdx[r3] = i3; }
    }
    __syncthreads();

    if (tid == 0) {
        float kth = sVal[49];
        int M = 50;
        while (M < TOP_CAP && sVal[M] == kth) ++M;
        s_M = M;
    }
    __syncthreads();
    int M = s_M;
    if (tid < M) sExp[tid] = exp((double)sVal[tid] - (double)sVal[0]);
    __syncthreads();

    if (tid == 0) {
        double denom = 0.0;
#pragma unroll 1
        for (int i = 0; i < M; ++i) denom += sExp[i];
        double cum = 0.0;
        int J = M - 1;
#pragma unroll 1
        for (int i = 0; i < M; ++i) {
            cum += sExp[i] / denom;
            if (cum > 0.9) { J = i; break; }
        }
        float t = sVal[J];
        // raw preimage of x==t via +-4-ulp scan around t*0.8f (winner guaranteed in range)
        float w = t * 0.8f;
        unsigned wb = __float_as_uint(w);
        unsigned lo = 0xFFFFFFFFu, hi = 0u;
        for (int d = -4; d <= 4; ++d) {
            unsigned ub = wb + (unsigned)d;
            if (__uint_as_float(ub) / 0.8f == t) { if (ub < lo) lo = ub; if (ub > hi) hi = ub; }
        }
        rowParam[row] = make_uint4(lo, hi, (unsigned)sIdx[J], 0u);
    }
}

extern "C" void kernel_launch(void* const* d_in, const int* in_sizes, int n_in,
                              void* d_out, int out_size, void* d_ws, size_t ws_size,
                              hipStream_t stream) {
    const float* logits = (const float*)d_in[0];
    const int* ids = (const int*)d_in[1];
    float* out = (float*)d_out;

    uint4* rowParam = (uint4*)((char*)d_ws + WS_ROWPARAM);
    unsigned* bcnt = (unsigned*)((char*)d_ws + WS_BCNT);
    unsigned* mask = (unsigned*)((char*)d_ws + WS_MASK);
    uint2* gcand = (uint2*)((char*)d_ws + WS_GCAND);

    if (ws_size >= WS_NEED) {
        // fast path: prep(mask+gather, no pre-zero) -> select -> apply
        prep_kernel<<<PREP_BLOCKS, 256, 0, stream>>>((const float4*)logits, ids, gcand, bcnt, mask);
        select_kernel<<<ROWS, 256, 0, stream>>>(logits, gcand, bcnt, rowParam);
    } else {
        mask_only_kernel<<<B_, 256, 0, stream>>>(ids, mask);
        row_thresh_kernel<<<ROWS, RT_THREADS, 0, stream>>>(logits, rowParam);
    }
    apply_kernel<<<(NVEC / 2 + 255) / 256, 256, 0, stream>>>((const float4*)logits, rowParam,
                                                             mask, (float4*)out);
}

// Round 8
// 60.243 us; speedup vs baseline: 8.4563x; 1.2507x over previous
//
#include <hip/hip_runtime.h>
#include <stdint.h>

#define V 50257
#define B_ 64
#define S_ 8
#define ROWS (B_ * S_)
#define L_ 2048
#define NEG_INF -1000000000.0f
#define PEN_NEG (-1200000000.0f)   // NEG_INF * 1.2f, exact in fp32
#define MASK_WORDS_PER_B 1571      // ceil(50257/32)
#define TOTAL (ROWS * V)           // 25,731,584
#define NVEC (TOTAL / 4)           // 6,432,896 (exact)
#define TOP_CAP 64                 // top-k=50 plus headroom for exact ties at kth
#define TRAW 2.8f                  // raw cutoff; E[cnt]=128/row, P(cnt<50)~1e-14
#define GBLK_F4 1571               // float4s per prep block (spans <= 2 rows)
#define GBLOCKS_G ((NVEC + GBLK_F4 - 1) / GBLK_F4)   // 4095
#define GCAP_BLK 64                // per-block candidate region (mean 16, sd 4)
#define CAPROW 512                 // per-row candidate cap in select
#define NPRESW ((GBLK_F4 * 4 + 31) / 32)             // 197 words range-presence

// ---- workspace layout ----
// fast path: bcnt + gcand (no pre-zero needed; prep writes every bcnt slot)
#define WS_BCNT    0                                    // 4095 u32 -> pad 16384
#define WS_GCAND   16384                                // 4095*64*8 = 2,096,640
#define WS_NEED    (WS_GCAND + (size_t)GBLOCKS_G * GCAP_BLK * 8)   // ~2.11 MB
// fallback layout (disjoint use; only when ws too small for fast path)
#define WS_ROWPARAM 0                                   // 512 * 16 B
#define WS_MASK     8192                                // 402176 B
#define WS_FB_NEED  (WS_MASK + MASK_WORDS_PER_B * B_ * 4)

__device__ __forceinline__ unsigned fkey(float f) {
    unsigned u = __float_as_uint(f);
    return (u & 0x80000000u) ? ~u : (u | 0x80000000u);
}

__device__ __forceinline__ int blockReduceSum256(int v, int tid, int* s4) {
#pragma unroll
    for (int off = 32; off; off >>= 1) v += __shfl_down(v, off);
    __syncthreads();
    if ((tid & 63) == 0) s4[tid >> 6] = v;
    __syncthreads();
    return s4[0] + s4[1] + s4[2] + s4[3];
}

// ---------------- prep: gather + background output fill (one pass over logits) ----------------

// Block owns f4 range [blk*GBLK_F4, end). Reads its slice once, gathers raw
// candidates (v >= TRAW) into a private gcand region (plain count store, no
// global atomics), and writes the output BACKGROUND for its whole range:
// -1e9 everywhere, -1.2e9 where a s==7-row token is present in input_ids.
// Kept tokens (~50/row) are overwritten later by select's scatter.
__global__ __launch_bounds__(256) void prep_kernel(const float4* __restrict__ in4,
                                                   const int* __restrict__ ids,
                                                   float4* __restrict__ out4,
                                                   uint2* __restrict__ gcand,
                                                   unsigned* __restrict__ bcnt) {
    const int blk = blockIdx.x;
    const int tid = threadIdx.x;
    const int start = blk * GBLK_F4;
    const int end = min(start + GBLK_F4, NVEC);
    const unsigned baseE = (unsigned)start << 2;
    const unsigned endE = (unsigned)end << 2;

    __shared__ unsigned pres[NPRESW];
    __shared__ uint2 buf[GCAP_BLK];
    __shared__ int lcnt;

    // issue all 7 logits loads first (clamped, unconditional) for MLP
    float4 va[7];
#pragma unroll
    for (int k = 0; k < 7; ++k) {
        int i = start + tid + k * 256;
        va[k] = in4[min(i, NVEC - 1)];
    }

    for (int w = tid; w < NPRESW; w += 256) pres[w] = 0u;
    if (tid == 0) lcnt = 0;
    __syncthreads();

    // presence bits from the (at most one) s==7 row intersecting this range
    {
        unsigned r0 = baseE / (unsigned)V, r1 = (endE - 1u) / (unsigned)V;
        unsigned rl = ((r0 & 7u) == 7u) ? r0 : (((r1 & 7u) == 7u) ? r1 : 0xFFFFFFFFu);
        if (rl != 0xFFFFFFFFu) {
            const int* bp = ids + (rl >> 3) * L_;
            unsigned rowBase = rl * (unsigned)V;
#pragma unroll
            for (int k = 0; k < L_ / 256; ++k) {
                unsigned ge = rowBase + (unsigned)bp[k * 256 + tid];
                if (ge >= baseE && ge < endE) {
                    unsigned off = ge - baseE;
                    atomicOr(&pres[off >> 5], 1u << (off & 31));
                }
            }
        }
    }
    __syncthreads();

#pragma unroll
    for (int k = 0; k < 7; ++k) {
        int i = start + tid + k * 256;
        if (i < end) {
            float4 a = va[k];
            unsigned e = (unsigned)i << 2;
            if (a.x >= TRAW) { int p = atomicAdd(&lcnt, 1); if (p < GCAP_BLK) buf[p] = make_uint2(e,      __float_as_uint(a.x)); }
            if (a.y >= TRAW) { int p = atomicAdd(&lcnt, 1); if (p < GCAP_BLK) buf[p] = make_uint2(e + 1u, __float_as_uint(a.y)); }
            if (a.z >= TRAW) { int p = atomicAdd(&lcnt, 1); if (p < GCAP_BLK) buf[p] = make_uint2(e + 2u, __float_as_uint(a.z)); }
            if (a.w >= TRAW) { int p = atomicAdd(&lcnt, 1); if (p < GCAP_BLK) buf[p] = make_uint2(e + 3u, __float_as_uint(a.w)); }
            unsigned off = e - baseE;                 // off % 4 == 0 -> all 4 bits in one word
            unsigned pw = pres[off >> 5] >> (off & 31u);
            float4 bg;
            bg.x = (pw & 1u) ? PEN_NEG : NEG_INF;
            bg.y = (pw & 2u) ? PEN_NEG : NEG_INF;
            bg.z = (pw & 4u) ? PEN_NEG : NEG_INF;
            bg.w = (pw & 8u) ? PEN_NEG : NEG_INF;
            out4[i] = bg;
        }
    }
    __syncthreads();
    if (tid == 0) bcnt[blk] = (unsigned)lcnt;         // > GCAP_BLK flags overflow
    int take = min(lcnt, GCAP_BLK);
    for (int j = tid; j < take; j += 256) gcand[(size_t)blk * GCAP_BLK + j] = buf[j];
}

// ---------------- select: exact per-row threshold + scatter of kept values ----------------

// One 256-thread block per row. Exact reference semantics incl. fp32 ties:
// kth = 50th largest of x=v/0.8f; kept = ALL x >= kth; stable (x desc, idx asc)
// order like np.argsort(-x); f64 softmax+cumsum decision. Then scatters the
// kept values (x, with rep-penalty for s==7 rows) over prep's background.
__global__ __launch_bounds__(256) void select_kernel(const float* __restrict__ logits,
                                                     const int* __restrict__ ids,
                                                     const uint2* __restrict__ gcand,
                                                     const unsigned* __restrict__ bcnt,
                                                     float* __restrict__ out) {
    const int row = blockIdx.x;
    const int tid = threadIdx.x;
    __shared__ float cX[CAPROW];
    __shared__ unsigned cR[CAPROW];
    __shared__ int cI[CAPROW];
    __shared__ float sVal[TOP_CAP];
    __shared__ int sIdx[TOP_CAP];
    __shared__ double sExp[TOP_CAP];
    __shared__ unsigned presRow[MASK_WORDS_PER_B];
    __shared__ int s_c, s_M, s_bad, s_ti;
    __shared__ float s_t;
    __shared__ int s_red[4];

    const float* rp = logits + (size_t)row * V;
    const unsigned e0 = (unsigned)row * (unsigned)V;
    if (tid == 0) { s_c = 0; s_bad = 0; }
    __syncthreads();

    {   // scan the <=9 prep-block regions overlapping this row; filter by row
        const int b0 = (int)((e0 >> 2) / GBLK_F4);
        const int b1 = (int)(((e0 + V - 1) >> 2) / GBLK_F4);
        for (int blk = b0; blk <= b1; ++blk) {
            unsigned c = bcnt[blk];
            if (c > GCAP_BLK && tid == 0) s_bad = 1;
            int take = min((int)c, GCAP_BLK);
            for (int j = tid; j < take; j += 256) {
                uint2 u = gcand[(size_t)blk * GCAP_BLK + j];
                if (u.x / (unsigned)V == (unsigned)row) {
                    int p = atomicAdd(&s_c, 1);
                    if (p < CAPROW) {
                        cR[p] = u.y;
                        cX[p] = __uint_as_float(u.y) / 0.8f;
                        cI[p] = (int)(u.x - e0);
                    }
                }
            }
        }
    }
    __syncthreads();
    int cnt = s_c;
    if (s_bad || cnt < 50 || cnt > CAPROW) {
        // Pathological-only exact fallback: bisect raw key space for the 50th
        // largest, re-gather with 2-ulp slack (covers /0.8 merging distinct raws).
        unsigned lo = 0u, hi = 0xFFFFFFFFu;
        while (lo < hi) {
            unsigned mid = lo + ((hi - lo) >> 1) + 1u;
            int c = 0;
            for (int j = tid; j < V; j += 256) c += (int)(fkey(rp[j]) >= mid);
            c = blockReduceSum256(c, tid, s_red);
            if (c >= 50) lo = mid; else hi = mid - 1u;
        }
        unsigned gl = (lo > 2u) ? lo - 2u : 0u;
        __syncthreads();
        if (tid == 0) s_c = 0;
        __syncthreads();
        for (int j = tid; j < V; j += 256) {
            float v = rp[j];
            if (fkey(v) >= gl) {
                int p = atomicAdd(&s_c, 1);
                if (p < CAPROW) { cR[p] = __float_as_uint(v); cX[p] = v / 0.8f; cI[p] = j; }
            }
        }
        __syncthreads();
        cnt = min(s_c, CAPROW);
    }

    if (tid < TOP_CAP) { sVal[tid] = -3.4e38f; sIdx[tid] = 0x7FFFFFFF; }
    __syncthreads();

    // Rank-sort: each thread owns <=2 candidates; j-loop is an LDS broadcast
    // read (conflict-free). Ranks unique via (x desc, token idx asc) key.
    {
        float v0 = -3.4e38f, v1 = -3.4e38f;
        int i0 = 0x7FFFFFFF, i1 = 0x7FFFFFFF;
        if (tid < cnt) { v0 = cX[tid]; i0 = cI[tid]; }
        if (tid + 256 < cnt) { v1 = cX[tid + 256]; i1 = cI[tid + 256]; }
        int r0 = 0, r1 = 0;
        for (int j = 0; j < cnt; ++j) {
            float w = cX[j];
            int wi = cI[j];
            r0 += (w > v0) || (w == v0 && wi < i0);
            r1 += (w > v1) || (w == v1 && wi < i1);
        }
        if (tid < cnt && r0 < TOP_CAP) { sVal[r0] = v0; sIdx[r0] = i0; }
        if (tid + 256 < cnt && r1 < TOP_CAP) { sVal[r1] = v1; sIdx[r1] = i1; }
    }
    __syncthreads();

    if (tid == 0) {
        float kth = sVal[49];
        int M = 50;
        while (M < TOP_CAP && sVal[M] == kth) ++M;   // include exact ties at kth
        s_M = M;
    }
    __syncthreads();
    int M = s_M;
    if (tid < M) sExp[tid] = exp((double)sVal[tid] - (double)sVal[0]);
    __syncthreads();
    if (tid == 0) {
        double denom = 0.0;
        for (int i = 0; i < M; ++i) denom += sExp[i];
        double cum = 0.0;
        int J = M - 1;
        for (int i = 0; i < M; ++i) {
            cum += sExp[i] / denom;
            if (cum > 0.9) { J = i; break; }
        }
        s_t = sVal[J];
        s_ti = sIdx[J];
    }

    // presence bitmask for the rep-penalty (only s==7 rows; block-uniform branch)
    if ((row & 7) == 7) {
        __syncthreads();
        for (int w = tid; w < MASK_WORDS_PER_B; w += 256) presRow[w] = 0u;
        __syncthreads();
        const int* bp = ids + (row >> 3) * L_;
#pragma unroll
        for (int k = 0; k < L_ / 256; ++k) {
            int t = bp[k * 256 + tid];
            atomicOr(&presRow[t >> 5], 1u << (t & 31));
        }
    }
    __syncthreads();

    // scatter kept values over the background (kept set is always a subset of
    // the candidate set: t >= kth >= TRAW/0.8 on the non-fallback path)
    float t = s_t;
    int tie = s_ti;
    float* orow = out + (size_t)row * V;
    const bool pen = (row & 7) == 7;
    for (int j = tid; j < cnt; j += 256) {
        float x = cX[j];
        int tok = cI[j];
        bool keep = (x > t) || (x == t && tok <= tie);
        if (keep) {
            float oo = x;   // exact v/0.8f, matches reference bits
            if (pen && ((presRow[tok >> 5] >> (tok & 31)) & 1u))
                oo = (oo < 0.0f) ? oo * 1.2f : oo * (1.0f / 1.2f);
            orow[tok] = oo;
        }
    }
}

// ---------------- safety fallback (ws too small; round-7 proven path) ----------------
#define CAND_CAP 4096
#define RT_THREADS 1024

__global__ __launch_bounds__(256) void mask_only_kernel(const int* __restrict__ ids,
                                                        unsigned* __restrict__ mask) {
    const int tid = threadIdx.x;
    const int b = blockIdx.x;
    __shared__ unsigned lds[MASK_WORDS_PER_B];
    for (int w = tid; w < MASK_WORDS_PER_B; w += 256) lds[w] = 0u;
    __syncthreads();
    const int* bp = ids + b * L_;
#pragma unroll
    for (int k = 0; k < L_ / 256; ++k) {
        int t = bp[k * 256 + tid];
        atomicOr(&lds[t >> 5], 1u << (t & 31));
    }
    __syncthreads();
    unsigned* mp = mask + b * MASK_WORDS_PER_B;
    for (int w = tid; w < MASK_WORDS_PER_B; w += 256) mp[w] = lds[w];
}

__device__ __forceinline__ int blockReduceSum1024(int v, int tid, int* s16) {
#pragma unroll
    for (int off = 32; off; off >>= 1) v += __shfl_down(v, off);
    __syncthreads();
    if ((tid & 63) == 0) s16[tid >> 6] = v;
    __syncthreads();
    int t = 0;
#pragma unroll
    for (int k = 0; k < RT_THREADS / 64; ++k) t += s16[k];
    return t;
}

__global__ __launch_bounds__(RT_THREADS, 8) void row_thresh_kernel(
        const float* __restrict__ logits, uint4* __restrict__ rowParam) {
    const int tid = threadIdx.x;
    const int row = blockIdx.x;
    if (row >= ROWS) return;
    const float* rp = logits + (size_t)row * V;

    __shared__ float candV[CAND_CAP];
    __shared__ int   candI[CAND_CAP];
    __shared__ float sVal[TOP_CAP];
    __shared__ int   sIdx[TOP_CAP];
    __shared__ double sExp[TOP_CAP];
    __shared__ int s_cnt, s_M;
    __shared__ int s_red[RT_THREADS / 64];

    const unsigned mis = (unsigned)(((size_t)row * (size_t)V) & 3u);
    const int a0 = (int)((4u - mis) & 3u);
    const int nv = (V - a0) >> 2;
    const int tailStart = a0 + (nv << 2);
    const float4* vp = reinterpret_cast<const float4*>(rp + a0);

    float TR = 2.4f;
    int cnt = 0;
    for (int attempt = 0; attempt < 12; ++attempt) {
        if (tid == 0) s_cnt = 0;
        __syncthreads();
        for (int base = tid; base < nv; base += 4 * RT_THREADS) {
            int i1 = base + RT_THREADS, i2 = base + 2 * RT_THREADS, i3 = base + 3 * RT_THREADS;
            float4 a = vp[base];
            float4 b = vp[i1 < nv ? i1 : nv - 1];
            float4 c = vp[i2 < nv ? i2 : nv - 1];
            float4 d = vp[i3 < nv ? i3 : nv - 1];
            float va[16] = {a.x, a.y, a.z, a.w, b.x, b.y, b.z, b.w,
                            c.x, c.y, c.z, c.w, d.x, d.y, d.z, d.w};
            int ib[4] = {base, i1, i2, i3};
            bool ok[4] = {true, i1 < nv, i2 < nv, i3 < nv};
#pragma unroll
            for (int q = 0; q < 4; ++q) {
                if (!ok[q]) continue;
#pragma unroll
                for (int cc = 0; cc < 4; ++cc) {
                    float v = va[q * 4 + cc];
                    if (v >= TR) {
                        int p = atomicAdd(&s_cnt, 1);
                        if (p < CAND_CAP) { candV[p] = v / 0.8f; candI[p] = a0 + (ib[q] << 2) + cc; }
                    }
                }
            }
        }
        if (tid < a0) {
            float v = rp[tid];
            if (v >= TR) {
                int p = atomicAdd(&s_cnt, 1);
                if (p < CAND_CAP) { candV[p] = v / 0.8f; candI[p] = tid; }
            }
        }
        if (tid < V - tailStart) {
            float v = rp[tailStart + tid];
            if (v >= TR) {
                int p = atomicAdd(&s_cnt, 1);
                if (p < CAND_CAP) { candV[p] = v / 0.8f; candI[p] = tailStart + tid; }
            }
        }
        __syncthreads();
        cnt = s_cnt;
        if (cnt >= 50 && cnt <= CAND_CAP) break;
        if (cnt < 50) TR -= 1.2f; else TR += 1.2f;
        __syncthreads();
    }
    if (cnt > CAND_CAP) cnt = CAND_CAP;

    if (tid < TOP_CAP) { sVal[tid] = -3.4e38f; sIdx[tid] = 0x7FFFFFFF; }
    __syncthreads();

    {
        float v0 = (tid < cnt) ? candV[tid] : -3.4e38f;
        int i0 = (tid < cnt) ? candI[tid] : 0x7FFFFFFF;
        float v1 = (tid + RT_THREADS < cnt) ? candV[tid + RT_THREADS] : -3.4e38f;
        int i1 = (tid + RT_THREADS < cnt) ? candI[tid + RT_THREADS] : 0x7FFFFFFF;
        float v2 = (tid + 2 * RT_THREADS < cnt) ? candV[tid + 2 * RT_THREADS] : -3.4e38f;
        int i2 = (tid + 2 * RT_THREADS < cnt) ? candI[tid + 2 * RT_THREADS] : 0x7FFFFFFF;
        float v3 = (tid + 3 * RT_THREADS < cnt) ? candV[tid + 3 * RT_THREADS] : -3.4e38f;
        int i3 = (tid + 3 * RT_THREADS < cnt) ? candI[tid + 3 * RT_THREADS] : 0x7FFFFFFF;
        int r0 = 0, r1 = 0, r2 = 0, r3 = 0;
        for (int j = 0; j < cnt; ++j) {
            float w = candV[j];
            int wi = candI[j];
            r0 += (w > v0) || (w == v0 && wi < i0);
            r1 += (w > v1) || (w == v1 && wi < i1);
            r2 += (w > v2) || (w == v2 && wi < i2);
            r3 += (w > v3) || (w == v3 && wi < i3);
        }
        if (tid < cnt && r0 < TOP_CAP) { sVal[r0] = v0; sIdx[r0] = i0; }
        if (tid + RT_THREADS < cnt && r1 < TOP_CAP) { sVal[r1] = v1; sIdx[r1] = i1; }
        if (tid + 2 * RT_THREADS < cnt && r2 < TOP_CAP) { sVal[r2] = v2; sIdx[r2] = i2; }
        if (tid + 3 * RT_THREADS < cnt && r3 < TOP_CAP) { sVal[r3] = v3; sIdx[r3] = i3; }
    }
    __syncthreads();

    if (tid == 0) {
        float kth = sVal[49];
        int M = 50;
        while (M < TOP_CAP && sVal[M] == kth) ++M;
        s_M = M;
    }
    __syncthreads();
    int M = s_M;
    if (tid < M) sExp[tid] = exp((double)sVal[tid] - (double)sVal[0]);
    __syncthreads();

    if (tid == 0) {
        double denom = 0.0;
#pragma unroll 1
        for (int i = 0; i < M; ++i) denom += sExp[i];
        double cum = 0.0;
        int J = M - 1;
#pragma unroll 1
        for (int i = 0; i < M; ++i) {
            cum += sExp[i] / denom;
            if (cum > 0.9) { J = i; break; }
        }
        float t = sVal[J];
        float w = t * 0.8f;
        unsigned wb = __float_as_uint(w);
        unsigned lo = 0xFFFFFFFFu, hi = 0u;
        for (int d = -4; d <= 4; ++d) {
            unsigned ub = wb + (unsigned)d;
            if (__uint_as_float(ub) / 0.8f == t) { if (ub < lo) lo = ub; if (ub > hi) hi = ub; }
        }
        rowParam[row] = make_uint4(lo, hi, (unsigned)sIdx[J], 0u);
    }
}

__global__ __launch_bounds__(256) void apply_kernel(const float4* __restrict__ in4,
                                                    const uint4* __restrict__ rowParam,
                                                    const unsigned* __restrict__ mask,
                                                    float4* __restrict__ out4) {
    int gid = blockIdx.x * 256 + threadIdx.x;
    int i0 = gid << 1;
    if (i0 >= NVEC) return;
    float4 a = in4[i0];
    float4 b = in4[i0 + 1];
    unsigned e = (unsigned)i0 << 2;
    unsigned row = e / (unsigned)V;
    unsigned tok0 = e - row * (unsigned)V;
    uint4 p0 = rowParam[row];
    bool crosses = (tok0 + 7u >= (unsigned)V);
    uint4 p1 = crosses ? rowParam[row + 1] : p0;
    float xs[8] = {a.x, a.y, a.z, a.w, b.x, b.y, b.z, b.w};
    float o[8];
#pragma unroll
    for (int c = 0; c < 8; ++c) {
        unsigned tok = tok0 + (unsigned)c;
        unsigned r = row;
        uint4 pp = p0;
        if (tok >= (unsigned)V) { tok -= (unsigned)V; r = row + 1u; pp = p1; }
        float v = xs[c];
        float vlo = __uint_as_float(pp.x);
        float vhi = __uint_as_float(pp.y);
        bool keep = (v > vhi) || (v >= vlo && tok <= pp.z);
        float oo = keep ? v * 1.25f : NEG_INF;
        if ((r & 7u) == 7u) {
            unsigned w = mask[(r >> 3) * MASK_WORDS_PER_B + (tok >> 5)];
            if ((w >> (tok & 31u)) & 1u) oo = (oo < 0.0f) ? oo * 1.2f : oo * (1.0f / 1.2f);
        }
        o[c] = oo;
    }
    out4[i0] = make_float4(o[0], o[1], o[2], o[3]);
    out4[i0 + 1] = make_float4(o[4], o[5], o[6], o[7]);
}

extern "C" void kernel_launch(void* const* d_in, const int* in_sizes, int n_in,
                              void* d_out, int out_size, void* d_ws, size_t ws_size,
                              hipStream_t stream) {
    const float* logits = (const float*)d_in[0];
    const int* ids = (const int*)d_in[1];
    float* out = (float*)d_out;

    if (ws_size >= WS_NEED) {
        unsigned* bcnt = (unsigned*)((char*)d_ws + WS_BCNT);
        uint2* gcand = (uint2*)((char*)d_ws + WS_GCAND);
        // 2-kernel fast path: prep (read logits once, gather + background fill)
        // -> select (exact threshold + scatter kept values)
        prep_kernel<<<GBLOCKS_G, 256, 0, stream>>>((const float4*)logits, ids, (float4*)out,
                                                   gcand, bcnt);
        select_kernel<<<ROWS, 256, 0, stream>>>(logits, ids, gcand, bcnt, out);
    } else {
        uint4* rowParam = (uint4*)((char*)d_ws + WS_ROWPARAM);
        unsigned* mask = (unsigned*)((char*)d_ws + WS_MASK);
        mask_only_kernel<<<B_, 256, 0, stream>>>(ids, mask);
        row_thresh_kernel<<<ROWS, RT_THREADS, 0, stream>>>(logits, rowParam);
        apply_kernel<<<(NVEC / 2 + 255) / 256, 256, 0, stream>>>((const float4*)logits, rowParam,
                                                                 mask, (float4*)out);
    }
}